// Round 6
// baseline (1193.209 us; speedup 1.0000x reference)
//
#include <hip/hip_runtime.h>

// Problem constants (reference: T=64 time steps, B=SEQ=128 batch, IN=256, H=512)
#define TT 64
#define BB 128
#define IND 256
#define HH 512
#define GG 2048      // 4*H
#define NCC 10
#define KFLAT 65536  // SEQ*H
#define HP2 520      // bf16 LDS row stride (512 + 8)
#define SP 36        // GEMM LDS short stride

typedef __attribute__((ext_vector_type(8))) short bf16x8;
typedef __attribute__((ext_vector_type(4))) float floatx4;

__device__ __forceinline__ unsigned short f2bf(float x) {   // RNE round to bf16
    unsigned u = __builtin_bit_cast(unsigned, x);
    u += 0x7fffu + ((u >> 16) & 1u);
    return (unsigned short)(u >> 16);
}
__device__ __forceinline__ float bf2f(unsigned short h) {
    unsigned u = ((unsigned)h) << 16;
    return __builtin_bit_cast(float, u);
}
__device__ __forceinline__ float pk2f(unsigned u) {
    float hi = __builtin_bit_cast(float, u & 0xffff0000u);
    float lo = __builtin_bit_cast(float, u << 16);
    return hi + lo;
}

// ---------------------------------------------------------------------------
// Elementwise: fp32 -> packed split-bf16 (hi<<16 | lo)
// ---------------------------------------------------------------------------
__global__ __launch_bounds__(256) void pack_split_kernel(
    const float* __restrict__ src, unsigned* __restrict__ dst, int n)
{
    for (int i = blockIdx.x * 256 + threadIdx.x; i < n; i += gridDim.x * 256) {
        float f = src[i];
        unsigned short hb = f2bf(f);
        unsigned short lb = f2bf(f - bf2f(hb));
        dst[i] = ((unsigned)hb << 16) | lb;
    }
}

// ---------------------------------------------------------------------------
// MFMA GEMM on packed split-bf16 (proven R6): layer-0 input transform only.
// ---------------------------------------------------------------------------
__global__ __launch_bounds__(256) void gemm_pk_mfma(
    const unsigned* __restrict__ A, const unsigned* __restrict__ W,
    const float* __restrict__ b0, const float* __restrict__ b1,
    float* __restrict__ C, int K, int N)
{
    __shared__ short Ahi[128][SP], Alo[128][SP], Whi[128][SP], Wlo[128][SP];

    const int tid  = threadIdx.x;
    const int lane = tid & 63;
    const int wv   = tid >> 6;
    const int wm   = (wv & 1) * 64;
    const int wn   = (wv >> 1) * 64;
    const int l15  = lane & 15;
    const int quad = lane >> 4;
    const int m0   = blockIdx.x * 128;
    const int n0   = blockIdx.y * 128;

    floatx4 acc[4][4];
    #pragma unroll
    for (int i = 0; i < 4; ++i)
        #pragma unroll
        for (int j = 0; j < 4; ++j)
            acc[i][j] = (floatx4){0.f, 0.f, 0.f, 0.f};

    for (int kc = 0; kc < K; kc += 32) {
        #pragma unroll
        for (int it = 0; it < 4; ++it) {
            const int lin = it * 256 + tid;
            const int row = lin >> 3;
            const int c4  = (lin & 7) * 4;
            uint4 va = *(const uint4*)&A[(size_t)(m0 + row) * K + kc + c4];
            uint2 ah, al;
            ah.x = (va.x >> 16) | (va.y & 0xffff0000u);
            ah.y = (va.z >> 16) | (va.w & 0xffff0000u);
            al.x = (va.x & 0xffffu) | (va.y << 16);
            al.y = (va.z & 0xffffu) | (va.w << 16);
            *(uint2*)&Ahi[row][c4] = ah;
            *(uint2*)&Alo[row][c4] = al;
            uint4 vw = *(const uint4*)&W[(size_t)(n0 + row) * K + kc + c4];
            uint2 wh, wl;
            wh.x = (vw.x >> 16) | (vw.y & 0xffff0000u);
            wh.y = (vw.z >> 16) | (vw.w & 0xffff0000u);
            wl.x = (vw.x & 0xffffu) | (vw.y << 16);
            wl.y = (vw.z & 0xffffu) | (vw.w << 16);
            *(uint2*)&Whi[row][c4] = wh;
            *(uint2*)&Wlo[row][c4] = wl;
        }
        __syncthreads();

        bf16x8 afh[4], afl[4], bfh[4], bfl[4];
        #pragma unroll
        for (int i = 0; i < 4; ++i) {
            afh[i] = *(const bf16x8*)&Ahi[wm + i * 16 + l15][quad * 8];
            afl[i] = *(const bf16x8*)&Alo[wm + i * 16 + l15][quad * 8];
            bfh[i] = *(const bf16x8*)&Whi[wn + i * 16 + l15][quad * 8];
            bfl[i] = *(const bf16x8*)&Wlo[wn + i * 16 + l15][quad * 8];
        }
        #pragma unroll
        for (int i = 0; i < 4; ++i)
            #pragma unroll
            for (int j = 0; j < 4; ++j) {
                acc[i][j] = __builtin_amdgcn_mfma_f32_16x16x32_bf16(afh[i], bfh[j], acc[i][j], 0, 0, 0);
                acc[i][j] = __builtin_amdgcn_mfma_f32_16x16x32_bf16(afh[i], bfl[j], acc[i][j], 0, 0, 0);
                acc[i][j] = __builtin_amdgcn_mfma_f32_16x16x32_bf16(afl[i], bfh[j], acc[i][j], 0, 0, 0);
            }
        __syncthreads();
    }

    #pragma unroll
    for (int i = 0; i < 4; ++i) {
        #pragma unroll
        for (int j = 0; j < 4; ++j) {
            const int n = n0 + wn + j * 16 + l15;
            const float bias = b0[n] + b1[n];
            #pragma unroll
            for (int r = 0; r < 4; ++r) {
                const int m = m0 + wm + i * 16 + quad * 4 + r;
                C[(size_t)m * N + n] = acc[i][j][r] + bias;
            }
        }
    }
}

// ---------------------------------------------------------------------------
// Stage 8 tagged h-cells into LDS hi/lo planes — ATOMIC (L2-bypassing) path.
// Used only as the retry fallback; returns nonzero on tag miss.
// ---------------------------------------------------------------------------
__device__ __forceinline__ unsigned stage8_atomic(
    const unsigned long long* __restrict__ src, int bb, int kk, unsigned exp,
    short (*Hs_hi)[HP2], short (*Hs_lo)[HP2])
{
    unsigned long long q0 = __hip_atomic_load(src + 0, __ATOMIC_RELAXED, __HIP_MEMORY_SCOPE_AGENT);
    unsigned long long q1 = __hip_atomic_load(src + 1, __ATOMIC_RELAXED, __HIP_MEMORY_SCOPE_AGENT);
    unsigned long long q2 = __hip_atomic_load(src + 2, __ATOMIC_RELAXED, __HIP_MEMORY_SCOPE_AGENT);
    unsigned long long q3 = __hip_atomic_load(src + 3, __ATOMIC_RELAXED, __HIP_MEMORY_SCOPE_AGENT);
    unsigned c0 = (unsigned)q0, c1 = (unsigned)(q0 >> 32);
    unsigned c2 = (unsigned)q1, c3 = (unsigned)(q1 >> 32);
    unsigned c4 = (unsigned)q2, c5 = (unsigned)(q2 >> 32);
    unsigned c6 = (unsigned)q3, c7 = (unsigned)(q3 >> 32);
    unsigned bad = ((c0 ^ exp) | (c1 ^ exp) | (c2 ^ exp) | (c3 ^ exp)
                  | (c4 ^ exp) | (c5 ^ exp) | (c6 ^ exp) | (c7 ^ exp)) & 0xFu;
    uint4 hiv, lov;
    hiv.x = (c0 >> 16) | (c1 & 0xffff0000u);
    hiv.y = (c2 >> 16) | (c3 & 0xffff0000u);
    hiv.z = (c4 >> 16) | (c5 & 0xffff0000u);
    hiv.w = (c6 >> 16) | (c7 & 0xffff0000u);
    lov.x = (c0 & 0xFFF0u) | ((c1 & 0xFFF0u) << 16);
    lov.y = (c2 & 0xFFF0u) | ((c3 & 0xFFF0u) << 16);
    lov.z = (c4 & 0xFFF0u) | ((c5 & 0xFFF0u) << 16);
    lov.w = (c6 & 0xFFF0u) | ((c7 & 0xFFF0u) << 16);
    *(uint4*)&Hs_hi[bb][kk] = hiv;
    *(uint4*)&Hs_lo[bb][kk] = lov;
    return bad;
}

// ---------------------------------------------------------------------------
// Stage 8 tagged h-cells — PLAIN CACHED path (fast). Only issued after the
// counter handshake; tag check retained, mismatch retries via stage8_atomic.
// ---------------------------------------------------------------------------
__device__ __forceinline__ unsigned stage8_plain(
    const unsigned* __restrict__ src, int bb, int kk, unsigned exp,
    short (*Hs_hi)[HP2], short (*Hs_lo)[HP2])
{
    const uint4 v0 = *(const uint4*)(src);
    const uint4 v1 = *(const uint4*)(src + 4);
    unsigned bad = ((v0.x ^ exp) | (v0.y ^ exp) | (v0.z ^ exp) | (v0.w ^ exp)
                  | (v1.x ^ exp) | (v1.y ^ exp) | (v1.z ^ exp) | (v1.w ^ exp)) & 0xFu;
    uint4 hiv, lov;
    hiv.x = (v0.x >> 16) | (v0.y & 0xffff0000u);
    hiv.y = (v0.z >> 16) | (v0.w & 0xffff0000u);
    hiv.z = (v1.x >> 16) | (v1.y & 0xffff0000u);
    hiv.w = (v1.z >> 16) | (v1.w & 0xffff0000u);
    lov.x = (v0.x & 0xFFF0u) | ((v0.y & 0xFFF0u) << 16);
    lov.y = (v0.z & 0xFFF0u) | ((v0.w & 0xFFF0u) << 16);
    lov.z = (v1.x & 0xFFF0u) | ((v1.y & 0xFFF0u) << 16);
    lov.w = (v1.z & 0xFFF0u) | ((v1.w & 0xFFF0u) << 16);
    *(uint4*)&Hs_hi[bb][kk] = hiv;
    *(uint4*)&Hs_lo[bb][kk] = lov;
    return bad;
}

// Tile stage over a generic (start, stride, count) index walk.
__device__ __forceinline__ void stage_tile_g(
    const unsigned* __restrict__ base, unsigned exp,
    int tstart, int pcount, int pstride,
    short (*Hs_hi)[HP2], short (*Hs_lo)[HP2])
{
    unsigned miss = 0;
    for (int p = 0; p < pcount; ++p) {
        const int idx = p * pstride + tstart;
        unsigned bad = stage8_plain(base + idx, idx >> 9, idx & 511,
                                    exp, Hs_hi, Hs_lo);
        miss |= (bad ? 1u : 0u) << p;
    }
    while (miss) {
        for (int p = 0; p < pcount; ++p) {
            if (miss & (1u << p)) {
                const int idx = p * pstride + tstart;
                if (!stage8_atomic((const unsigned long long*)(base + idx),
                                   idx >> 9, idx & 511, exp, Hs_hi, Hs_lo))
                    miss &= ~(1u << p);
            }
        }
    }
}

// Agent-scope relaxed counter poll (ready when all 4 producer waves have
// published). BOUNDED + throttled: the counter is a latency optimization —
// the tag-retry staging path is a complete correctness protocol by itself,
// so falling through can never produce wrong results.
__device__ __forceinline__ void spin_cnt(const unsigned* p) {
    int n = 0;
    while (__hip_atomic_load(p, __ATOMIC_RELAXED, __HIP_MEMORY_SCOPE_AGENT) < 4u) {
        __builtin_amdgcn_s_sleep(1);   // ~64 cyc: keeps the poll storm polite
        if (++n > 65536) break;
    }
}

// ---------------------------------------------------------------------------
// FUSED two-layer persistent LSTM — R6: de-barriered handshake.
// Blocks 0..127 = layer 0; 128..255 = layer 1. WG (bt, jsl): batches
// [bt*32,+32) x 16 hidden units. 512 threads: waves 0-3 = R pipeline,
// waves 4-7 = X pipeline (layer 1) / staging help (layer 0).
//
// Handshake (counter-based, 2 barriers/step):
//  * publish: each R-wave stores its h cells (paired 8B tagged stores),
//    drains ITS OWN vmcnt (s_waitcnt vmcnt(0), wave-level), lane0 does
//    atomicAdd(cnt[layer][t+1][bt][jsl], 1). Ready == 4. No block barrier.
//  * consume: each staging thread reads exactly ONE producer slice (its
//    col window (tid*8)&511 lies in one 16-unit j-slice), so it self-polls
//    that one counter, then stages. No barrier between poll and stage.
//  * barriers: B2 (stage -> MFMA-read) and B3 (Gs-write -> update-read).
//    B1/B4 removed; Gs(t) read vs Gs(t+1) write is fenced by B2(t+1);
//    Ra/Xa(t+1) write vs C(t) readers is fenced by B3(t).
// Tags (lo nibble, gen%9) remain the correctness net; counters are purely
// a latency optimization (bounded spin, degrade to tag-retry).
// ---------------------------------------------------------------------------
__global__ __launch_bounds__(512, 2) void lstm_fused(
    const float* __restrict__ xg,     // [T][B][4H] layer-0 (biases included)
    const float* __restrict__ w_hh0,  // [4H][H] fp32
    const float* __restrict__ w_ih1,  // [4H][H] fp32
    const float* __restrict__ w_hh1,  // [4H][H] fp32
    const float* __restrict__ b_ih1, const float* __restrict__ b_hh1,
    unsigned* __restrict__ hpack0,    // [T+1][B][H] tagged, block 0 zeroed
    unsigned* __restrict__ hpack1,    // [T+1][B][H] tagged, block 0 zeroed
    unsigned* __restrict__ flags)     // [2][T+1][4][32] wave counters (zeroed)
{
    __shared__ short Ra_hi[32][HP2], Ra_lo[32][HP2];   // recurrent h tile
    __shared__ short Xa_hi[32][HP2], Xa_lo[32][HP2];   // layer-1 input h0 tile
    __shared__ float GsR[64][33];
    __shared__ float GsX[64][33];

    const int tid  = threadIdx.x;          // 0..511
    const int lane = tid & 63;
    const int wv   = tid >> 6;             // 0..7
    const bool isR = wv < 4;               // R-pipeline waves
    const int gate = wv & 3;               // gate for MFMA (both roles)
    const bool isB = blockIdx.x >= 128;
    const int blk  = blockIdx.x & 127;
    const int bt   = blk & 3;
    const int jsl  = blk >> 2;             // producer j-slice id 0..31
    const int j0   = jsl * 16;             // 16-unit slice
    const int l15  = lane & 15;
    const int quad = lane >> 4;
    const int tid_x = tid - 256;           // X-thread linear id (valid if !isR)
    const int slice = (lane >> 1);         // col-slice this thread stages (0..31)

    // ---- preload weight frags: ONE array per thread, role-dependent ----
    bf16x8 wf_hi[16], wf_lo[16];
    {
        const float* wsrc = isR ? (isB ? w_hh1 : w_hh0) : w_ih1;
        if (isR || isB) {
            const float* wrow = wsrc + (size_t)(gate * HH + j0 + l15) * HH + quad * 8;
            #pragma unroll
            for (int kc = 0; kc < 16; ++kc) {
                float f[8];
                *(float4*)&f[0] = *(const float4*)&wrow[kc * 32];
                *(float4*)&f[4] = *(const float4*)&wrow[kc * 32 + 4];
                bf16x8 vh, vl;
                #pragma unroll
                for (int j = 0; j < 8; ++j) {
                    unsigned short hb = f2bf(f[j]);
                    vh[j] = (short)hb;
                    vl[j] = (short)f2bf(f[j] - bf2f(hb));
                }
                wf_hi[kc] = vh; wf_lo[kc] = vl;
            }
        }
    }

    // update-phase roles (R-threads): 2 j-adjacent cells of one batch row
    const int ju  = (tid & 7) * 2;         // 0,2,...,14
    const int bu2 = (tid >> 3) & 31;       // 0..31
    float bi0=0.f,bi1=0.f,bf0_=0.f,bf1_=0.f,bg0=0.f,bg1=0.f,bo0=0.f,bo1=0.f;
    if (isB && isR) {
        bi0 = b_ih1[j0+ju]        + b_hh1[j0+ju];
        bi1 = b_ih1[j0+ju+1]      + b_hh1[j0+ju+1];
        bf0_= b_ih1[HH+j0+ju]     + b_hh1[HH+j0+ju];
        bf1_= b_ih1[HH+j0+ju+1]   + b_hh1[HH+j0+ju+1];
        bg0 = b_ih1[2*HH+j0+ju]   + b_hh1[2*HH+j0+ju];
        bg1 = b_ih1[2*HH+j0+ju+1] + b_hh1[2*HH+j0+ju+1];
        bo0 = b_ih1[3*HH+j0+ju]   + b_hh1[3*HH+j0+ju];
        bo1 = b_ih1[3*HH+j0+ju+1] + b_hh1[3*HH+j0+ju+1];
    }

    // zero GsX once (layer-0 never writes it; update always reads it)
    for (int i = tid; i < 64 * 33; i += 512)
        ((float*)GsX)[i] = 0.f;
    __syncthreads();

    unsigned* hp_rec = isB ? hpack1 : hpack0;
    const int layerBase = isB ? 65 : 0;
    float c0 = 0.f, c1 = 0.f;

    for (int t = 0; t < TT; ++t) {
        const unsigned* rec_base = hp_rec + (size_t)t * (BB * HH) + (size_t)bt * 32 * HH;
        const unsigned* inp_base = hpack0 + (size_t)(t + 1) * (BB * HH) + (size_t)bt * 32 * HH;
        const unsigned expR = (unsigned)t % 9u;
        const unsigned expX = (unsigned)(t + 1) % 9u;
        const unsigned* cR = flags + ((layerBase + t) * 4 + bt) * 32;
        const unsigned* cX = flags + ((t + 1) * 4 + bt) * 32;

        // layer-0 R-threads: xg prefetch (overlaps poll + staging latency)
        float2 xgv[4];
        if (!isB && isR) {
            const float* base = xg + (size_t)t * (BB * GG)
                              + (size_t)(bt * 32 + bu2) * GG + j0 + ju;
            #pragma unroll
            for (int g = 0; g < 4; ++g)
                xgv[g] = *(const float2*)&base[g * HH];
        }

        // ---- self-poll (each thread gates only its own staging slice) ----
        if (isB) {
            if (isR) { if (t > 0) spin_cnt(cR + slice); }
            else     { spin_cnt(cX + slice); }
        } else {
            if (t > 0) spin_cnt(cR + slice);
        }
        asm volatile("" ::: "memory");   // no staging loads hoisted above poll

        // ---- staging (per-thread, flag-gated; tag-retry fallback inside) ----
        if (isB) {
            if (isR) stage_tile_g(rec_base, expR, tid * 8,   8, 2048, Ra_hi, Ra_lo);
            else     stage_tile_g(inp_base, expX, tid_x * 8, 8, 2048, Xa_hi, Xa_lo);
        } else {
            stage_tile_g(rec_base, expR, tid * 8, 4, 4096, Ra_hi, Ra_lo);
        }
        __syncthreads();                                   // B2

        // ---- MFMA + Gs writes ----
        if (isR) {
            floatx4 a0 = {0.f,0.f,0.f,0.f}, a1 = {0.f,0.f,0.f,0.f};
            #pragma unroll
            for (int kc = 0; kc < 16; ++kc) {
                const int off = kc * 32 + quad * 8;
                bf16x8 r0h = *(const bf16x8*)&Ra_hi[l15][off];
                bf16x8 r0l = *(const bf16x8*)&Ra_lo[l15][off];
                bf16x8 r1h = *(const bf16x8*)&Ra_hi[16 + l15][off];
                bf16x8 r1l = *(const bf16x8*)&Ra_lo[16 + l15][off];
                a0 = __builtin_amdgcn_mfma_f32_16x16x32_bf16(wf_hi[kc], r0h, a0, 0, 0, 0);
                a1 = __builtin_amdgcn_mfma_f32_16x16x32_bf16(wf_hi[kc], r1h, a1, 0, 0, 0);
                a0 = __builtin_amdgcn_mfma_f32_16x16x32_bf16(wf_hi[kc], r0l, a0, 0, 0, 0);
                a1 = __builtin_amdgcn_mfma_f32_16x16x32_bf16(wf_hi[kc], r1l, a1, 0, 0, 0);
                a0 = __builtin_amdgcn_mfma_f32_16x16x32_bf16(wf_lo[kc], r0h, a0, 0, 0, 0);
                a1 = __builtin_amdgcn_mfma_f32_16x16x32_bf16(wf_lo[kc], r1h, a1, 0, 0, 0);
            }
            #pragma unroll
            for (int r = 0; r < 4; ++r) {
                GsR[gate * 16 + quad * 4 + r][l15]      = a0[r];
                GsR[gate * 16 + quad * 4 + r][16 + l15] = a1[r];
            }
        } else if (isB) {
            floatx4 a0 = {0.f,0.f,0.f,0.f}, a1 = {0.f,0.f,0.f,0.f};
            #pragma unroll
            for (int kc = 0; kc < 16; ++kc) {
                const int off = kc * 32 + quad * 8;
                bf16x8 x0h = *(const bf16x8*)&Xa_hi[l15][off];
                bf16x8 x0l = *(const bf16x8*)&Xa_lo[l15][off];
                bf16x8 x1h = *(const bf16x8*)&Xa_hi[16 + l15][off];
                bf16x8 x1l = *(const bf16x8*)&Xa_lo[16 + l15][off];
                a0 = __builtin_amdgcn_mfma_f32_16x16x32_bf16(wf_hi[kc], x0h, a0, 0, 0, 0);
                a1 = __builtin_amdgcn_mfma_f32_16x16x32_bf16(wf_hi[kc], x1h, a1, 0, 0, 0);
                a0 = __builtin_amdgcn_mfma_f32_16x16x32_bf16(wf_hi[kc], x0l, a0, 0, 0, 0);
                a1 = __builtin_amdgcn_mfma_f32_16x16x32_bf16(wf_hi[kc], x1l, a1, 0, 0, 0);
                a0 = __builtin_amdgcn_mfma_f32_16x16x32_bf16(wf_lo[kc], x0h, a0, 0, 0, 0);
                a1 = __builtin_amdgcn_mfma_f32_16x16x32_bf16(wf_lo[kc], x1h, a1, 0, 0, 0);
            }
            #pragma unroll
            for (int r = 0; r < 4; ++r) {
                GsX[gate * 16 + quad * 4 + r][l15]      = a0[r];
                GsX[gate * 16 + quad * 4 + r][16 + l15] = a1[r];
            }
        }
        __syncthreads();                                   // B3

        // ---- update (R-threads): 2 j-adjacent cells, one 8B tagged store;
        //      per-wave drain + counter publication (no block barrier) ----
        if (isR) {
            const unsigned tag = (unsigned)(t + 1) % 9u;
            float gi0 = GsR[ju][bu2]      + GsX[ju][bu2];
            float gi1 = GsR[ju+1][bu2]    + GsX[ju+1][bu2];
            float gf0 = GsR[16+ju][bu2]   + GsX[16+ju][bu2];
            float gf1 = GsR[17+ju][bu2]   + GsX[17+ju][bu2];
            float gg0 = GsR[32+ju][bu2]   + GsX[32+ju][bu2];
            float gg1 = GsR[33+ju][bu2]   + GsX[33+ju][bu2];
            float go0 = GsR[48+ju][bu2]   + GsX[48+ju][bu2];
            float go1 = GsR[49+ju][bu2]   + GsX[49+ju][bu2];
            if (isB) {
                gi0 += bi0; gi1 += bi1; gf0 += bf0_; gf1 += bf1_;
                gg0 += bg0; gg1 += bg1; go0 += bo0; go1 += bo1;
            } else {
                gi0 += xgv[0].x; gi1 += xgv[0].y;
                gf0 += xgv[1].x; gf1 += xgv[1].y;
                gg0 += xgv[2].x; gg1 += xgv[2].y;
                go0 += xgv[3].x; go1 += xgv[3].y;
            }
            const float si0 = 1.f / (1.f + __expf(-gi0));
            const float sf0 = 1.f / (1.f + __expf(-gf0));
            const float tg0 = 2.f / (1.f + __expf(-2.f * gg0)) - 1.f;
            const float so0 = 1.f / (1.f + __expf(-go0));
            c0 = sf0 * c0 + si0 * tg0;
            const float th0 = 2.f / (1.f + __expf(-2.f * c0)) - 1.f;
            const float h0v = so0 * th0;
            const float si1 = 1.f / (1.f + __expf(-gi1));
            const float sf1 = 1.f / (1.f + __expf(-gf1));
            const float tg1 = 2.f / (1.f + __expf(-2.f * gg1)) - 1.f;
            const float so1 = 1.f / (1.f + __expf(-go1));
            c1 = sf1 * c1 + si1 * tg1;
            const float th1 = 2.f / (1.f + __expf(-2.f * c1)) - 1.f;
            const float h1v = so1 * th1;
            const unsigned short hb0 = f2bf(h0v);
            const unsigned short lb0 = f2bf(h0v - bf2f(hb0));
            const unsigned short hb1 = f2bf(h1v);
            const unsigned short lb1 = f2bf(h1v - bf2f(hb1));
            const unsigned pk0 = ((unsigned)hb0 << 16) | ((unsigned)lb0 & 0xFFF0u) | tag;
            const unsigned pk1 = ((unsigned)hb1 << 16) | ((unsigned)lb1 & 0xFFF0u) | tag;
            const unsigned long long pk64 =
                (unsigned long long)pk0 | ((unsigned long long)pk1 << 32);
            __hip_atomic_store(
                (unsigned long long*)&hp_rec[(size_t)(t + 1) * (BB * HH)
                    + (size_t)(bt * 32 + bu2) * HH + j0 + ju],
                pk64, __ATOMIC_RELAXED, __HIP_MEMORY_SCOPE_AGENT);

            // per-wave drain: wave-level vmcnt(0) covers all 64 lanes' stores
            asm volatile("s_waitcnt vmcnt(0)" ::: "memory");
            if (lane == 0)
                __hip_atomic_fetch_add(
                    (unsigned*)(flags + ((layerBase + (t + 1)) * 4 + bt) * 32 + jsl),
                    1u, __ATOMIC_RELAXED, __HIP_MEMORY_SCOPE_AGENT);
        }
        // no B4: Gs(t) reads vs Gs(t+1) writes fenced by next step's B2;
        // Ra/Xa(t+1) staging vs this step's readers fenced by B3 above.
    }
}

// ---------------------------------------------------------------------------
// Classifier split-K partial GEMM on tagged h cells (mask tag nibble)
// ---------------------------------------------------------------------------
__global__ __launch_bounds__(256) void cls_partial_kernel(
    const unsigned* __restrict__ A, const float* __restrict__ W,
    float* __restrict__ part)
{
    const int n0 = blockIdx.x * 64;
    const int s  = blockIdx.y;
    const int kbase = s * 2048;
    const int tid = threadIdx.x;
    __shared__ float As[32][68];
    __shared__ float Bs[32][68];
    const int tm = tid >> 4, tn = tid & 15;
    float acc[4][4] = {};

    for (int kt = 0; kt < 2048; kt += 32) {
        #pragma unroll
        for (int q = tid; q < 512; q += 256) {
            const int mm = q >> 3;
            const int kq = q & 7;
            uint4 v = *(const uint4*)&A[(size_t)mm * KFLAT + kbase + kt + kq * 4];
            As[kq*4+0][mm] = pk2f(v.x & 0xFFFFFFF0u); As[kq*4+1][mm] = pk2f(v.y & 0xFFFFFFF0u);
            As[kq*4+2][mm] = pk2f(v.z & 0xFFFFFFF0u); As[kq*4+3][mm] = pk2f(v.w & 0xFFFFFFF0u);
            float4 w = *(const float4*)&W[(size_t)(n0 + mm) * KFLAT + kbase + kt + kq * 4];
            Bs[kq*4+0][mm] = w.x; Bs[kq*4+1][mm] = w.y;
            Bs[kq*4+2][mm] = w.z; Bs[kq*4+3][mm] = w.w;
        }
        __syncthreads();
        #pragma unroll
        for (int k = 0; k < 32; ++k) {
            float4 a = *(const float4*)&As[k][tm * 4];
            float4 b = *(const float4*)&Bs[k][tn * 4];
            acc[0][0] += a.x*b.x; acc[0][1] += a.x*b.y; acc[0][2] += a.x*b.z; acc[0][3] += a.x*b.w;
            acc[1][0] += a.y*b.x; acc[1][1] += a.y*b.y; acc[1][2] += a.y*b.z; acc[1][3] += a.y*b.w;
            acc[2][0] += a.z*b.x; acc[2][1] += a.z*b.y; acc[2][2] += a.z*b.z; acc[2][3] += a.z*b.w;
            acc[3][0] += a.w*b.x; acc[3][1] += a.w*b.y; acc[3][2] += a.w*b.z; acc[3][3] += a.w*b.w;
        }
        __syncthreads();
    }
    #pragma unroll
    for (int i = 0; i < 4; ++i) {
        const int m = tm * 4 + i;
        #pragma unroll
        for (int j = 0; j < 4; ++j) {
            part[((size_t)s * 64 + m) * 512 + n0 + tn * 4 + j] = acc[i][j];
        }
    }
}

// ---------------------------------------------------------------------------
// Classifier finish (unchanged)
// ---------------------------------------------------------------------------
__global__ __launch_bounds__(256) void cls_final_kernel(
    const float* __restrict__ part, const float* __restrict__ b1,
    const float* __restrict__ w2, const float* __restrict__ b2,
    float* __restrict__ out)
{
    const int t = blockIdx.x;
    __shared__ float hm[512];
    for (int n = threadIdx.x; n < 512; n += 256) {
        float sacc = b1[n];
        for (int sl = 0; sl < 32; ++sl)
            sacc += part[((size_t)sl * 64 + t) * 512 + n];
        hm[n] = fmaxf(sacc, 0.f);
    }
    __syncthreads();
    if (threadIdx.x < NCC) {
        float sacc = b2[threadIdx.x];
        const float* wr = w2 + (size_t)threadIdx.x * 512;
        for (int n = 0; n < 512; ++n) sacc += hm[n] * wr[n];
        out[t * NCC + threadIdx.x] = sacc;
    }
}

// ---------------------------------------------------------------------------
extern "C" void kernel_launch(void* const* d_in, const int* in_sizes, int n_in,
                              void* d_out, int out_size, void* d_ws, size_t ws_size,
                              hipStream_t stream)
{
    const float* x     = (const float*)d_in[0];
    const float* w_ih0 = (const float*)d_in[1];
    const float* w_hh0 = (const float*)d_in[2];
    const float* b_ih0 = (const float*)d_in[3];
    const float* b_hh0 = (const float*)d_in[4];
    const float* w_ih1 = (const float*)d_in[5];
    const float* w_hh1 = (const float*)d_in[6];
    const float* b_ih1 = (const float*)d_in[7];
    const float* b_hh1 = (const float*)d_in[8];
    const float* w1    = (const float*)d_in[9];
    const float* b1    = (const float*)d_in[10];
    const float* w2    = (const float*)d_in[11];
    const float* b2    = (const float*)d_in[12];
    float* out = (float*)d_out;

    // Workspace (~102.1 MB): hpack1 region is ALIASED over xpk/w0pk (dead
    // after the layer-0 GEMM). All t>=1 h reads are counter-gated (zeroed
    // each launch) and tag-checked, so no 0xFF scrub is needed.
    // flags alias the part region (part written only after lstm_fused).
    float*    ws     = (float*)d_ws;
    float*    xg     = ws;                                      // 64 MB
    unsigned* hpack0 = (unsigned*)(xg + (size_t)8192 * 2048);   // 17.04 MB
    unsigned* hpack1 = hpack0 + (size_t)65 * BB * HH;           // 17.04 MB (aliased)
    unsigned* xpk    = hpack1;                                  // 8 MB   (dies at GEMM)
    unsigned* w0pk   = xpk + (size_t)8192 * IND;                // 2 MB   (dies at GEMM)
    float*    part   = (float*)(hpack1 + (size_t)65 * BB * HH); // 4 MB
    unsigned* flags  = (unsigned*)part;                         // 66.6 KB (dies at cls)

    // ---- pack layer-0 GEMM inputs ----
    pack_split_kernel<<<1024, 256, 0, stream>>>(x, xpk, 8192 * IND);
    pack_split_kernel<<<512,  256, 0, stream>>>(w_ih0, w0pk, GG * IND);
    hipMemsetAsync(hpack0, 0, (size_t)BB * HH * sizeof(unsigned), stream);  // h0 t=0
    hipMemsetAsync(flags, 0, (size_t)2 * 65 * 4 * 32 * sizeof(unsigned), stream);

    // ---- layer-0 input transform ----
    gemm_pk_mfma<<<dim3(8192 / 128, GG / 128), 256, 0, stream>>>(
        xpk, w0pk, b_ih0, b_hh0, xg, IND, GG);

    // ---- zero t=0 block of hpack1 (after GEMM: aliased region now dead) ----
    hipMemsetAsync(hpack1, 0, (size_t)BB * HH * sizeof(unsigned), stream);

    // ---- fused two-layer recurrence (512-thread wave-specialized blocks) ----
    lstm_fused<<<256, 512, 0, stream>>>(
        xg, w_hh0, w_ih1, w_hh1, b_ih1, b_hh1, hpack0, hpack1, flags);

    // ---- classifier (tagged h1, blocks 1..64) ----
    cls_partial_kernel<<<dim3(512 / 64, 32), 256, 0, stream>>>(
        hpack1 + (size_t)BB * HH, w1, part);
    cls_final_kernel<<<64, 256, 0, stream>>>(part, b1, w2, b2, out);
}

// Round 7
// 860.278 us; speedup vs baseline: 1.3870x; 1.3870x over previous
//
#include <hip/hip_runtime.h>

// Problem constants (reference: T=64 time steps, B=SEQ=128 batch, IN=256, H=512)
#define TT 64
#define BB 128
#define IND 256
#define HH 512
#define GG 2048      // 4*H
#define NCC 10
#define KFLAT 65536  // SEQ*H
#define HP2 520      // bf16 LDS row stride (512 + 8)
#define SP 36        // GEMM LDS short stride

typedef __attribute__((ext_vector_type(8))) short bf16x8;
typedef __attribute__((ext_vector_type(4))) float floatx4;

__device__ __forceinline__ unsigned short f2bf(float x) {   // RNE round to bf16
    unsigned u = __builtin_bit_cast(unsigned, x);
    u += 0x7fffu + ((u >> 16) & 1u);
    return (unsigned short)(u >> 16);
}
__device__ __forceinline__ float bf2f(unsigned short h) {
    unsigned u = ((unsigned)h) << 16;
    return __builtin_bit_cast(float, u);
}
__device__ __forceinline__ float pk2f(unsigned u) {
    float hi = __builtin_bit_cast(float, u & 0xffff0000u);
    float lo = __builtin_bit_cast(float, u << 16);
    return hi + lo;
}

// ---------------------------------------------------------------------------
// Elementwise: fp32 -> packed split-bf16 (hi<<16 | lo)
// ---------------------------------------------------------------------------
__global__ __launch_bounds__(256) void pack_split_kernel(
    const float* __restrict__ src, unsigned* __restrict__ dst, int n)
{
    for (int i = blockIdx.x * 256 + threadIdx.x; i < n; i += gridDim.x * 256) {
        float f = src[i];
        unsigned short hb = f2bf(f);
        unsigned short lb = f2bf(f - bf2f(hb));
        dst[i] = ((unsigned)hb << 16) | lb;
    }
}

// ---------------------------------------------------------------------------
// MFMA GEMM on packed split-bf16 (proven R6): layer-0 input transform only.
// ---------------------------------------------------------------------------
__global__ __launch_bounds__(256) void gemm_pk_mfma(
    const unsigned* __restrict__ A, const unsigned* __restrict__ W,
    const float* __restrict__ b0, const float* __restrict__ b1,
    float* __restrict__ C, int K, int N)
{
    __shared__ short Ahi[128][SP], Alo[128][SP], Whi[128][SP], Wlo[128][SP];

    const int tid  = threadIdx.x;
    const int lane = tid & 63;
    const int wv   = tid >> 6;
    const int wm   = (wv & 1) * 64;
    const int wn   = (wv >> 1) * 64;
    const int l15  = lane & 15;
    const int quad = lane >> 4;
    const int m0   = blockIdx.x * 128;
    const int n0   = blockIdx.y * 128;

    floatx4 acc[4][4];
    #pragma unroll
    for (int i = 0; i < 4; ++i)
        #pragma unroll
        for (int j = 0; j < 4; ++j)
            acc[i][j] = (floatx4){0.f, 0.f, 0.f, 0.f};

    for (int kc = 0; kc < K; kc += 32) {
        #pragma unroll
        for (int it = 0; it < 4; ++it) {
            const int lin = it * 256 + tid;
            const int row = lin >> 3;
            const int c4  = (lin & 7) * 4;
            uint4 va = *(const uint4*)&A[(size_t)(m0 + row) * K + kc + c4];
            uint2 ah, al;
            ah.x = (va.x >> 16) | (va.y & 0xffff0000u);
            ah.y = (va.z >> 16) | (va.w & 0xffff0000u);
            al.x = (va.x & 0xffffu) | (va.y << 16);
            al.y = (va.z & 0xffffu) | (va.w << 16);
            *(uint2*)&Ahi[row][c4] = ah;
            *(uint2*)&Alo[row][c4] = al;
            uint4 vw = *(const uint4*)&W[(size_t)(n0 + row) * K + kc + c4];
            uint2 wh, wl;
            wh.x = (vw.x >> 16) | (vw.y & 0xffff0000u);
            wh.y = (vw.z >> 16) | (vw.w & 0xffff0000u);
            wl.x = (vw.x & 0xffffu) | (vw.y << 16);
            wl.y = (vw.z & 0xffffu) | (vw.w << 16);
            *(uint2*)&Whi[row][c4] = wh;
            *(uint2*)&Wlo[row][c4] = wl;
        }
        __syncthreads();

        bf16x8 afh[4], afl[4], bfh[4], bfl[4];
        #pragma unroll
        for (int i = 0; i < 4; ++i) {
            afh[i] = *(const bf16x8*)&Ahi[wm + i * 16 + l15][quad * 8];
            afl[i] = *(const bf16x8*)&Alo[wm + i * 16 + l15][quad * 8];
            bfh[i] = *(const bf16x8*)&Whi[wn + i * 16 + l15][quad * 8];
            bfl[i] = *(const bf16x8*)&Wlo[wn + i * 16 + l15][quad * 8];
        }
        #pragma unroll
        for (int i = 0; i < 4; ++i)
            #pragma unroll
            for (int j = 0; j < 4; ++j) {
                acc[i][j] = __builtin_amdgcn_mfma_f32_16x16x32_bf16(afh[i], bfh[j], acc[i][j], 0, 0, 0);
                acc[i][j] = __builtin_amdgcn_mfma_f32_16x16x32_bf16(afh[i], bfl[j], acc[i][j], 0, 0, 0);
                acc[i][j] = __builtin_amdgcn_mfma_f32_16x16x32_bf16(afl[i], bfh[j], acc[i][j], 0, 0, 0);
            }
        __syncthreads();
    }

    #pragma unroll
    for (int i = 0; i < 4; ++i) {
        #pragma unroll
        for (int j = 0; j < 4; ++j) {
            const int n = n0 + wn + j * 16 + l15;
            const float bias = b0[n] + b1[n];
            #pragma unroll
            for (int r = 0; r < 4; ++r) {
                const int m = m0 + wm + i * 16 + quad * 4 + r;
                C[(size_t)m * N + n] = acc[i][j][r] + bias;
            }
        }
    }
}

// ---------------------------------------------------------------------------
// Stage 8 tagged h-cells into LDS hi/lo planes — ATOMIC (L2-bypassing) path.
// Used only as the retry fallback; returns nonzero on tag miss.
// ---------------------------------------------------------------------------
__device__ __forceinline__ unsigned stage8_atomic(
    const unsigned long long* __restrict__ src, int bb, int kk, unsigned exp,
    short (*Hs_hi)[HP2], short (*Hs_lo)[HP2])
{
    unsigned long long q0 = __hip_atomic_load(src + 0, __ATOMIC_RELAXED, __HIP_MEMORY_SCOPE_AGENT);
    unsigned long long q1 = __hip_atomic_load(src + 1, __ATOMIC_RELAXED, __HIP_MEMORY_SCOPE_AGENT);
    unsigned long long q2 = __hip_atomic_load(src + 2, __ATOMIC_RELAXED, __HIP_MEMORY_SCOPE_AGENT);
    unsigned long long q3 = __hip_atomic_load(src + 3, __ATOMIC_RELAXED, __HIP_MEMORY_SCOPE_AGENT);
    unsigned c0 = (unsigned)q0, c1 = (unsigned)(q0 >> 32);
    unsigned c2 = (unsigned)q1, c3 = (unsigned)(q1 >> 32);
    unsigned c4 = (unsigned)q2, c5 = (unsigned)(q2 >> 32);
    unsigned c6 = (unsigned)q3, c7 = (unsigned)(q3 >> 32);
    unsigned bad = ((c0 ^ exp) | (c1 ^ exp) | (c2 ^ exp) | (c3 ^ exp)
                  | (c4 ^ exp) | (c5 ^ exp) | (c6 ^ exp) | (c7 ^ exp)) & 0xFu;
    uint4 hiv, lov;
    hiv.x = (c0 >> 16) | (c1 & 0xffff0000u);
    hiv.y = (c2 >> 16) | (c3 & 0xffff0000u);
    hiv.z = (c4 >> 16) | (c5 & 0xffff0000u);
    hiv.w = (c6 >> 16) | (c7 & 0xffff0000u);
    lov.x = (c0 & 0xFFF0u) | ((c1 & 0xFFF0u) << 16);
    lov.y = (c2 & 0xFFF0u) | ((c3 & 0xFFF0u) << 16);
    lov.z = (c4 & 0xFFF0u) | ((c5 & 0xFFF0u) << 16);
    lov.w = (c6 & 0xFFF0u) | ((c7 & 0xFFF0u) << 16);
    *(uint4*)&Hs_hi[bb][kk] = hiv;
    *(uint4*)&Hs_lo[bb][kk] = lov;
    return bad;
}

// ---------------------------------------------------------------------------
// Stage 8 tagged h-cells — PLAIN CACHED path (fast). Only issued after the
// counter handshake; tag check retained, mismatch retries via stage8_atomic.
// ---------------------------------------------------------------------------
__device__ __forceinline__ unsigned stage8_plain(
    const unsigned* __restrict__ src, int bb, int kk, unsigned exp,
    short (*Hs_hi)[HP2], short (*Hs_lo)[HP2])
{
    const uint4 v0 = *(const uint4*)(src);
    const uint4 v1 = *(const uint4*)(src + 4);
    unsigned bad = ((v0.x ^ exp) | (v0.y ^ exp) | (v0.z ^ exp) | (v0.w ^ exp)
                  | (v1.x ^ exp) | (v1.y ^ exp) | (v1.z ^ exp) | (v1.w ^ exp)) & 0xFu;
    uint4 hiv, lov;
    hiv.x = (v0.x >> 16) | (v0.y & 0xffff0000u);
    hiv.y = (v0.z >> 16) | (v0.w & 0xffff0000u);
    hiv.z = (v1.x >> 16) | (v1.y & 0xffff0000u);
    hiv.w = (v1.z >> 16) | (v1.w & 0xffff0000u);
    lov.x = (v0.x & 0xFFF0u) | ((v0.y & 0xFFF0u) << 16);
    lov.y = (v0.z & 0xFFF0u) | ((v0.w & 0xFFF0u) << 16);
    lov.z = (v1.x & 0xFFF0u) | ((v1.y & 0xFFF0u) << 16);
    lov.w = (v1.z & 0xFFF0u) | ((v1.w & 0xFFF0u) << 16);
    *(uint4*)&Hs_hi[bb][kk] = hiv;
    *(uint4*)&Hs_lo[bb][kk] = lov;
    return bad;
}

// Tile stage over a generic (start, stride, count) index walk.
__device__ __forceinline__ void stage_tile_g(
    const unsigned* __restrict__ base, unsigned exp,
    int tstart, int pcount, int pstride,
    short (*Hs_hi)[HP2], short (*Hs_lo)[HP2])
{
    unsigned miss = 0;
    for (int p = 0; p < pcount; ++p) {
        const int idx = p * pstride + tstart;
        unsigned bad = stage8_plain(base + idx, idx >> 9, idx & 511,
                                    exp, Hs_hi, Hs_lo);
        miss |= (bad ? 1u : 0u) << p;
    }
    while (miss) {
        for (int p = 0; p < pcount; ++p) {
            if (miss & (1u << p)) {
                const int idx = p * pstride + tstart;
                if (!stage8_atomic((const unsigned long long*)(base + idx),
                                   idx >> 9, idx & 511, exp, Hs_hi, Hs_lo))
                    miss &= ~(1u << p);
            }
        }
    }
}

// Agent-scope relaxed counter poll — TIGHT spin (no s_sleep: R6 showed the
// sleep+wide-poller combo inflates detect latency). BOUNDED: the counter is
// a latency optimization only; the tag-retry staging path is a complete
// correctness protocol, so falling through can never produce wrong results.
__device__ __forceinline__ void spin_cnt(const unsigned* p) {
    int n = 0;
    while (__hip_atomic_load(p, __ATOMIC_RELAXED, __HIP_MEMORY_SCOPE_AGENT) < 4u) {
        if (++n > 65536) break;
    }
}

// ---------------------------------------------------------------------------
// FUSED two-layer persistent LSTM — R7: R5 poll structure + early publish.
// Blocks 0..127 = layer 0; 128..255 = layer 1. WG (bt, jsl): batches
// [bt*32,+32) x 16 hidden units. 512 threads: waves 0-3 = R pipeline,
// waves 4-7 = X pipeline (layer 1) / staging help (layer 0).
//
// Handshake (3 barriers/step):
//  * publish: each R-wave stores its h cells (paired 8B tagged stores),
//    drains ITS OWN vmcnt (wave-level s_waitcnt), lane0 atomicAdds
//    cnt[layer][t+1][bt][jsl]. Ready == 4. No post-update block barrier
//    (B4 removed): flag leaves at fastest-wave-drain time.
//  * consume (R5-proven poller population): wave 0's 32 lanes poll the 32
//    R-counters; wave 4's 32 lanes poll the 32 X-counters (layer 1).
//    B1 gates staging on the polls.
//  * barriers: B1 (poll -> stage), B2 (stage -> MFMA-read), B3 (Gs-write
//    -> update-read). Gs(t) reads vs Gs(t+1) writes fenced by B2(t+1);
//    Ra/Xa(t+1) writes vs MFMA(t) reads fenced by B3(t).
// Tags (lo nibble, gen%9) remain the correctness net; counters are purely
// a latency optimization (bounded spin, degrade to tag-retry).
// ---------------------------------------------------------------------------
__global__ __launch_bounds__(512, 2) void lstm_fused(
    const float* __restrict__ xg,     // [T][B][4H] layer-0 (biases included)
    const float* __restrict__ w_hh0,  // [4H][H] fp32
    const float* __restrict__ w_ih1,  // [4H][H] fp32
    const float* __restrict__ w_hh1,  // [4H][H] fp32
    const float* __restrict__ b_ih1, const float* __restrict__ b_hh1,
    unsigned* __restrict__ hpack0,    // [T+1][B][H] tagged, block 0 zeroed
    unsigned* __restrict__ hpack1,    // [T+1][B][H] tagged, block 0 zeroed
    unsigned* __restrict__ flags)     // [2][T+1][4][32] wave counters (zeroed)
{
    __shared__ short Ra_hi[32][HP2], Ra_lo[32][HP2];   // recurrent h tile
    __shared__ short Xa_hi[32][HP2], Xa_lo[32][HP2];   // layer-1 input h0 tile
    __shared__ float GsR[64][33];
    __shared__ float GsX[64][33];

    const int tid  = threadIdx.x;          // 0..511
    const int lane = tid & 63;
    const int wv   = tid >> 6;             // 0..7
    const bool isR = wv < 4;               // R-pipeline waves
    const int gate = wv & 3;               // gate for MFMA (both roles)
    const bool isB = blockIdx.x >= 128;
    const int blk  = blockIdx.x & 127;
    const int bt   = blk & 3;
    const int jsl  = blk >> 2;             // producer j-slice id 0..31
    const int j0   = jsl * 16;             // 16-unit slice
    const int l15  = lane & 15;
    const int quad = lane >> 4;
    const int tid_x = tid - 256;           // X-thread linear id (valid if !isR)

    // ---- preload weight frags: ONE array per thread, role-dependent ----
    bf16x8 wf_hi[16], wf_lo[16];
    {
        const float* wsrc = isR ? (isB ? w_hh1 : w_hh0) : w_ih1;
        if (isR || isB) {
            const float* wrow = wsrc + (size_t)(gate * HH + j0 + l15) * HH + quad * 8;
            #pragma unroll
            for (int kc = 0; kc < 16; ++kc) {
                float f[8];
                *(float4*)&f[0] = *(const float4*)&wrow[kc * 32];
                *(float4*)&f[4] = *(const float4*)&wrow[kc * 32 + 4];
                bf16x8 vh, vl;
                #pragma unroll
                for (int j = 0; j < 8; ++j) {
                    unsigned short hb = f2bf(f[j]);
                    vh[j] = (short)hb;
                    vl[j] = (short)f2bf(f[j] - bf2f(hb));
                }
                wf_hi[kc] = vh; wf_lo[kc] = vl;
            }
        }
    }

    // update-phase roles (R-threads): 2 j-adjacent cells of one batch row
    const int ju  = (tid & 7) * 2;         // 0,2,...,14
    const int bu2 = (tid >> 3) & 31;       // 0..31
    float bi0=0.f,bi1=0.f,bf0_=0.f,bf1_=0.f,bg0=0.f,bg1=0.f,bo0=0.f,bo1=0.f;
    if (isB && isR) {
        bi0 = b_ih1[j0+ju]        + b_hh1[j0+ju];
        bi1 = b_ih1[j0+ju+1]      + b_hh1[j0+ju+1];
        bf0_= b_ih1[HH+j0+ju]     + b_hh1[HH+j0+ju];
        bf1_= b_ih1[HH+j0+ju+1]   + b_hh1[HH+j0+ju+1];
        bg0 = b_ih1[2*HH+j0+ju]   + b_hh1[2*HH+j0+ju];
        bg1 = b_ih1[2*HH+j0+ju+1] + b_hh1[2*HH+j0+ju+1];
        bo0 = b_ih1[3*HH+j0+ju]   + b_hh1[3*HH+j0+ju];
        bo1 = b_ih1[3*HH+j0+ju+1] + b_hh1[3*HH+j0+ju+1];
    }

    // zero GsX once (layer-0 never writes it; update always reads it)
    for (int i = tid; i < 64 * 33; i += 512)
        ((float*)GsX)[i] = 0.f;
    __syncthreads();

    unsigned* hp_rec = isB ? hpack1 : hpack0;
    const int layerBase = isB ? 65 : 0;
    float c0 = 0.f, c1 = 0.f;

    for (int t = 0; t < TT; ++t) {
        const unsigned* rec_base = hp_rec + (size_t)t * (BB * HH) + (size_t)bt * 32 * HH;
        const unsigned* inp_base = hpack0 + (size_t)(t + 1) * (BB * HH) + (size_t)bt * 32 * HH;
        const unsigned expR = (unsigned)t % 9u;
        const unsigned expX = (unsigned)(t + 1) % 9u;
        const unsigned* cR = flags + ((layerBase + t) * 4 + bt) * 32;
        const unsigned* cX = flags + ((t + 1) * 4 + bt) * 32;

        // layer-0 R-threads: xg prefetch (overlaps poll + staging latency)
        float2 xgv[4];
        if (!isB && isR) {
            const float* base = xg + (size_t)t * (BB * GG)
                              + (size_t)(bt * 32 + bu2) * GG + j0 + ju;
            #pragma unroll
            for (int g = 0; g < 4; ++g)
                xgv[g] = *(const float2*)&base[g * HH];
        }

        // ---- polls: wave 0 -> 32 R-counters, wave 4 -> 32 X-counters ----
        if (wv == 0 && lane < 32 && t > 0) spin_cnt(cR + lane);
        if (isB && wv == 4 && lane < 32) spin_cnt(cX + lane);
        __syncthreads();                                   // B1

        // ---- staging (flag-gated; tag-retry fallback inside) ----
        if (isB) {
            if (isR) stage_tile_g(rec_base, expR, tid * 8,   8, 2048, Ra_hi, Ra_lo);
            else     stage_tile_g(inp_base, expX, tid_x * 8, 8, 2048, Xa_hi, Xa_lo);
        } else {
            stage_tile_g(rec_base, expR, tid * 8, 4, 4096, Ra_hi, Ra_lo);
        }
        __syncthreads();                                   // B2

        // ---- MFMA + Gs writes ----
        if (isR) {
            floatx4 a0 = {0.f,0.f,0.f,0.f}, a1 = {0.f,0.f,0.f,0.f};
            #pragma unroll
            for (int kc = 0; kc < 16; ++kc) {
                const int off = kc * 32 + quad * 8;
                bf16x8 r0h = *(const bf16x8*)&Ra_hi[l15][off];
                bf16x8 r0l = *(const bf16x8*)&Ra_lo[l15][off];
                bf16x8 r1h = *(const bf16x8*)&Ra_hi[16 + l15][off];
                bf16x8 r1l = *(const bf16x8*)&Ra_lo[16 + l15][off];
                a0 = __builtin_amdgcn_mfma_f32_16x16x32_bf16(wf_hi[kc], r0h, a0, 0, 0, 0);
                a1 = __builtin_amdgcn_mfma_f32_16x16x32_bf16(wf_hi[kc], r1h, a1, 0, 0, 0);
                a0 = __builtin_amdgcn_mfma_f32_16x16x32_bf16(wf_hi[kc], r0l, a0, 0, 0, 0);
                a1 = __builtin_amdgcn_mfma_f32_16x16x32_bf16(wf_hi[kc], r1l, a1, 0, 0, 0);
                a0 = __builtin_amdgcn_mfma_f32_16x16x32_bf16(wf_lo[kc], r0h, a0, 0, 0, 0);
                a1 = __builtin_amdgcn_mfma_f32_16x16x32_bf16(wf_lo[kc], r1h, a1, 0, 0, 0);
            }
            #pragma unroll
            for (int r = 0; r < 4; ++r) {
                GsR[gate * 16 + quad * 4 + r][l15]      = a0[r];
                GsR[gate * 16 + quad * 4 + r][16 + l15] = a1[r];
            }
        } else if (isB) {
            floatx4 a0 = {0.f,0.f,0.f,0.f}, a1 = {0.f,0.f,0.f,0.f};
            #pragma unroll
            for (int kc = 0; kc < 16; ++kc) {
                const int off = kc * 32 + quad * 8;
                bf16x8 x0h = *(const bf16x8*)&Xa_hi[l15][off];
                bf16x8 x0l = *(const bf16x8*)&Xa_lo[l15][off];
                bf16x8 x1h = *(const bf16x8*)&Xa_hi[16 + l15][off];
                bf16x8 x1l = *(const bf16x8*)&Xa_lo[16 + l15][off];
                a0 = __builtin_amdgcn_mfma_f32_16x16x32_bf16(wf_hi[kc], x0h, a0, 0, 0, 0);
                a1 = __builtin_amdgcn_mfma_f32_16x16x32_bf16(wf_hi[kc], x1h, a1, 0, 0, 0);
                a0 = __builtin_amdgcn_mfma_f32_16x16x32_bf16(wf_hi[kc], x0l, a0, 0, 0, 0);
                a1 = __builtin_amdgcn_mfma_f32_16x16x32_bf16(wf_hi[kc], x1l, a1, 0, 0, 0);
                a0 = __builtin_amdgcn_mfma_f32_16x16x32_bf16(wf_lo[kc], x0h, a0, 0, 0, 0);
                a1 = __builtin_amdgcn_mfma_f32_16x16x32_bf16(wf_lo[kc], x1h, a1, 0, 0, 0);
            }
            #pragma unroll
            for (int r = 0; r < 4; ++r) {
                GsX[gate * 16 + quad * 4 + r][l15]      = a0[r];
                GsX[gate * 16 + quad * 4 + r][16 + l15] = a1[r];
            }
        }
        __syncthreads();                                   // B3

        // ---- update (R-threads): 2 j-adjacent cells, one 8B tagged store;
        //      per-wave drain + counter publication (no block barrier) ----
        if (isR) {
            const unsigned tag = (unsigned)(t + 1) % 9u;
            float gi0 = GsR[ju][bu2]      + GsX[ju][bu2];
            float gi1 = GsR[ju+1][bu2]    + GsX[ju+1][bu2];
            float gf0 = GsR[16+ju][bu2]   + GsX[16+ju][bu2];
            float gf1 = GsR[17+ju][bu2]   + GsX[17+ju][bu2];
            float gg0 = GsR[32+ju][bu2]   + GsX[32+ju][bu2];
            float gg1 = GsR[33+ju][bu2]   + GsX[33+ju][bu2];
            float go0 = GsR[48+ju][bu2]   + GsX[48+ju][bu2];
            float go1 = GsR[49+ju][bu2]   + GsX[49+ju][bu2];
            if (isB) {
                gi0 += bi0; gi1 += bi1; gf0 += bf0_; gf1 += bf1_;
                gg0 += bg0; gg1 += bg1; go0 += bo0; go1 += bo1;
            } else {
                gi0 += xgv[0].x; gi1 += xgv[0].y;
                gf0 += xgv[1].x; gf1 += xgv[1].y;
                gg0 += xgv[2].x; gg1 += xgv[2].y;
                go0 += xgv[3].x; go1 += xgv[3].y;
            }
            const float si0 = 1.f / (1.f + __expf(-gi0));
            const float sf0 = 1.f / (1.f + __expf(-gf0));
            const float tg0 = 2.f / (1.f + __expf(-2.f * gg0)) - 1.f;
            const float so0 = 1.f / (1.f + __expf(-go0));
            c0 = sf0 * c0 + si0 * tg0;
            const float th0 = 2.f / (1.f + __expf(-2.f * c0)) - 1.f;
            const float h0v = so0 * th0;
            const float si1 = 1.f / (1.f + __expf(-gi1));
            const float sf1 = 1.f / (1.f + __expf(-gf1));
            const float tg1 = 2.f / (1.f + __expf(-2.f * gg1)) - 1.f;
            const float so1 = 1.f / (1.f + __expf(-go1));
            c1 = sf1 * c1 + si1 * tg1;
            const float th1 = 2.f / (1.f + __expf(-2.f * c1)) - 1.f;
            const float h1v = so1 * th1;
            const unsigned short hb0 = f2bf(h0v);
            const unsigned short lb0 = f2bf(h0v - bf2f(hb0));
            const unsigned short hb1 = f2bf(h1v);
            const unsigned short lb1 = f2bf(h1v - bf2f(hb1));
            const unsigned pk0 = ((unsigned)hb0 << 16) | ((unsigned)lb0 & 0xFFF0u) | tag;
            const unsigned pk1 = ((unsigned)hb1 << 16) | ((unsigned)lb1 & 0xFFF0u) | tag;
            const unsigned long long pk64 =
                (unsigned long long)pk0 | ((unsigned long long)pk1 << 32);
            __hip_atomic_store(
                (unsigned long long*)&hp_rec[(size_t)(t + 1) * (BB * HH)
                    + (size_t)(bt * 32 + bu2) * HH + j0 + ju],
                pk64, __ATOMIC_RELAXED, __HIP_MEMORY_SCOPE_AGENT);

            // per-wave drain: wave-level vmcnt(0) covers all 64 lanes' stores
            asm volatile("s_waitcnt vmcnt(0)" ::: "memory");
            if (lane == 0)
                __hip_atomic_fetch_add(
                    (unsigned*)(flags + ((layerBase + (t + 1)) * 4 + bt) * 32 + jsl),
                    1u, __ATOMIC_RELAXED, __HIP_MEMORY_SCOPE_AGENT);
        }
        // no B4: Gs(t) reads vs Gs(t+1) writes fenced by next step's B2;
        // Ra/Xa(t+1) staging vs this step's readers fenced by B3 above.
    }
}

// ---------------------------------------------------------------------------
// Classifier split-K partial GEMM on tagged h cells (mask tag nibble)
// ---------------------------------------------------------------------------
__global__ __launch_bounds__(256) void cls_partial_kernel(
    const unsigned* __restrict__ A, const float* __restrict__ W,
    float* __restrict__ part)
{
    const int n0 = blockIdx.x * 64;
    const int s  = blockIdx.y;
    const int kbase = s * 2048;
    const int tid = threadIdx.x;
    __shared__ float As[32][68];
    __shared__ float Bs[32][68];
    const int tm = tid >> 4, tn = tid & 15;
    float acc[4][4] = {};

    for (int kt = 0; kt < 2048; kt += 32) {
        #pragma unroll
        for (int q = tid; q < 512; q += 256) {
            const int mm = q >> 3;
            const int kq = q & 7;
            uint4 v = *(const uint4*)&A[(size_t)mm * KFLAT + kbase + kt + kq * 4];
            As[kq*4+0][mm] = pk2f(v.x & 0xFFFFFFF0u); As[kq*4+1][mm] = pk2f(v.y & 0xFFFFFFF0u);
            As[kq*4+2][mm] = pk2f(v.z & 0xFFFFFFF0u); As[kq*4+3][mm] = pk2f(v.w & 0xFFFFFFF0u);
            float4 w = *(const float4*)&W[(size_t)(n0 + mm) * KFLAT + kbase + kt + kq * 4];
            Bs[kq*4+0][mm] = w.x; Bs[kq*4+1][mm] = w.y;
            Bs[kq*4+2][mm] = w.z; Bs[kq*4+3][mm] = w.w;
        }
        __syncthreads();
        #pragma unroll
        for (int k = 0; k < 32; ++k) {
            float4 a = *(const float4*)&As[k][tm * 4];
            float4 b = *(const float4*)&Bs[k][tn * 4];
            acc[0][0] += a.x*b.x; acc[0][1] += a.x*b.y; acc[0][2] += a.x*b.z; acc[0][3] += a.x*b.w;
            acc[1][0] += a.y*b.x; acc[1][1] += a.y*b.y; acc[1][2] += a.y*b.z; acc[1][3] += a.y*b.w;
            acc[2][0] += a.z*b.x; acc[2][1] += a.z*b.y; acc[2][2] += a.z*b.z; acc[2][3] += a.z*b.w;
            acc[3][0] += a.w*b.x; acc[3][1] += a.w*b.y; acc[3][2] += a.w*b.z; acc[3][3] += a.w*b.w;
        }
        __syncthreads();
    }
    #pragma unroll
    for (int i = 0; i < 4; ++i) {
        const int m = tm * 4 + i;
        #pragma unroll
        for (int j = 0; j < 4; ++j) {
            part[((size_t)s * 64 + m) * 512 + n0 + tn * 4 + j] = acc[i][j];
        }
    }
}

// ---------------------------------------------------------------------------
// Classifier finish (unchanged)
// ---------------------------------------------------------------------------
__global__ __launch_bounds__(256) void cls_final_kernel(
    const float* __restrict__ part, const float* __restrict__ b1,
    const float* __restrict__ w2, const float* __restrict__ b2,
    float* __restrict__ out)
{
    const int t = blockIdx.x;
    __shared__ float hm[512];
    for (int n = threadIdx.x; n < 512; n += 256) {
        float sacc = b1[n];
        for (int sl = 0; sl < 32; ++sl)
            sacc += part[((size_t)sl * 64 + t) * 512 + n];
        hm[n] = fmaxf(sacc, 0.f);
    }
    __syncthreads();
    if (threadIdx.x < NCC) {
        float sacc = b2[threadIdx.x];
        const float* wr = w2 + (size_t)threadIdx.x * 512;
        for (int n = 0; n < 512; ++n) sacc += hm[n] * wr[n];
        out[t * NCC + threadIdx.x] = sacc;
    }
}

// ---------------------------------------------------------------------------
extern "C" void kernel_launch(void* const* d_in, const int* in_sizes, int n_in,
                              void* d_out, int out_size, void* d_ws, size_t ws_size,
                              hipStream_t stream)
{
    const float* x     = (const float*)d_in[0];
    const float* w_ih0 = (const float*)d_in[1];
    const float* w_hh0 = (const float*)d_in[2];
    const float* b_ih0 = (const float*)d_in[3];
    const float* b_hh0 = (const float*)d_in[4];
    const float* w_ih1 = (const float*)d_in[5];
    const float* w_hh1 = (const float*)d_in[6];
    const float* b_ih1 = (const float*)d_in[7];
    const float* b_hh1 = (const float*)d_in[8];
    const float* w1    = (const float*)d_in[9];
    const float* b1    = (const float*)d_in[10];
    const float* w2    = (const float*)d_in[11];
    const float* b2    = (const float*)d_in[12];
    float* out = (float*)d_out;

    // Workspace (~102.1 MB): hpack1 region is ALIASED over xpk/w0pk (dead
    // after the layer-0 GEMM). All t>=1 h reads are counter-gated (zeroed
    // each launch) and tag-checked, so no 0xFF scrub is needed.
    // flags alias the part region (part written only after lstm_fused).
    float*    ws     = (float*)d_ws;
    float*    xg     = ws;                                      // 64 MB
    unsigned* hpack0 = (unsigned*)(xg + (size_t)8192 * 2048);   // 17.04 MB
    unsigned* hpack1 = hpack0 + (size_t)65 * BB * HH;           // 17.04 MB (aliased)
    unsigned* xpk    = hpack1;                                  // 8 MB   (dies at GEMM)
    unsigned* w0pk   = xpk + (size_t)8192 * IND;                // 2 MB   (dies at GEMM)
    float*    part   = (float*)(hpack1 + (size_t)65 * BB * HH); // 4 MB
    unsigned* flags  = (unsigned*)part;                         // 66.6 KB (dies at cls)

    // ---- pack layer-0 GEMM inputs ----
    pack_split_kernel<<<1024, 256, 0, stream>>>(x, xpk, 8192 * IND);
    pack_split_kernel<<<512,  256, 0, stream>>>(w_ih0, w0pk, GG * IND);
    hipMemsetAsync(hpack0, 0, (size_t)BB * HH * sizeof(unsigned), stream);  // h0 t=0
    hipMemsetAsync(flags, 0, (size_t)2 * 65 * 4 * 32 * sizeof(unsigned), stream);

    // ---- layer-0 input transform ----
    gemm_pk_mfma<<<dim3(8192 / 128, GG / 128), 256, 0, stream>>>(
        xpk, w0pk, b_ih0, b_hh0, xg, IND, GG);

    // ---- zero t=0 block of hpack1 (after GEMM: aliased region now dead) ----
    hipMemsetAsync(hpack1, 0, (size_t)BB * HH * sizeof(unsigned), stream);

    // ---- fused two-layer recurrence (512-thread wave-specialized blocks) ----
    lstm_fused<<<256, 512, 0, stream>>>(
        xg, w_hh0, w_ih1, w_hh1, b_ih1, b_hh1, hpack0, hpack1, flags);

    // ---- classifier (tagged h1, blocks 1..64) ----
    cls_partial_kernel<<<dim3(512 / 64, 32), 256, 0, stream>>>(
        hpack1 + (size_t)BB * HH, w1, part);
    cls_final_kernel<<<64, 256, 0, stream>>>(part, b1, w2, b2, out);
}

// Round 8
// 854.089 us; speedup vs baseline: 1.3971x; 1.0072x over previous
//
#include <hip/hip_runtime.h>

// Problem constants (reference: T=64 time steps, B=SEQ=128 batch, IN=256, H=512)
#define TT 64
#define BB 128
#define IND 256
#define HH 512
#define GG 2048      // 4*H
#define NCC 10
#define KFLAT 65536  // SEQ*H
#define HP2 520      // bf16 LDS row stride (512 + 8)
#define SP 36        // GEMM LDS short stride

typedef __attribute__((ext_vector_type(8))) short bf16x8;
typedef __attribute__((ext_vector_type(4))) float floatx4;

__device__ __forceinline__ unsigned short f2bf(float x) {   // RNE round to bf16
    unsigned u = __builtin_bit_cast(unsigned, x);
    u += 0x7fffu + ((u >> 16) & 1u);
    return (unsigned short)(u >> 16);
}
__device__ __forceinline__ float bf2f(unsigned short h) {
    unsigned u = ((unsigned)h) << 16;
    return __builtin_bit_cast(float, u);
}
__device__ __forceinline__ float pk2f(unsigned u) {
    float hi = __builtin_bit_cast(float, u & 0xffff0000u);
    float lo = __builtin_bit_cast(float, u << 16);
    return hi + lo;
}

// ---------------------------------------------------------------------------
// Elementwise: fp32 -> packed split-bf16 (hi<<16 | lo)
// ---------------------------------------------------------------------------
__global__ __launch_bounds__(256) void pack_split_kernel(
    const float* __restrict__ src, unsigned* __restrict__ dst, int n)
{
    for (int i = blockIdx.x * 256 + threadIdx.x; i < n; i += gridDim.x * 256) {
        float f = src[i];
        unsigned short hb = f2bf(f);
        unsigned short lb = f2bf(f - bf2f(hb));
        dst[i] = ((unsigned)hb << 16) | lb;
    }
}

// ---------------------------------------------------------------------------
// MFMA GEMM on packed split-bf16 (proven R6): layer-0 input transform only.
// ---------------------------------------------------------------------------
__global__ __launch_bounds__(256) void gemm_pk_mfma(
    const unsigned* __restrict__ A, const unsigned* __restrict__ W,
    const float* __restrict__ b0, const float* __restrict__ b1,
    float* __restrict__ C, int K, int N)
{
    __shared__ short Ahi[128][SP], Alo[128][SP], Whi[128][SP], Wlo[128][SP];

    const int tid  = threadIdx.x;
    const int lane = tid & 63;
    const int wv   = tid >> 6;
    const int wm   = (wv & 1) * 64;
    const int wn   = (wv >> 1) * 64;
    const int l15  = lane & 15;
    const int quad = lane >> 4;
    const int m0   = blockIdx.x * 128;
    const int n0   = blockIdx.y * 128;

    floatx4 acc[4][4];
    #pragma unroll
    for (int i = 0; i < 4; ++i)
        #pragma unroll
        for (int j = 0; j < 4; ++j)
            acc[i][j] = (floatx4){0.f, 0.f, 0.f, 0.f};

    for (int kc = 0; kc < K; kc += 32) {
        #pragma unroll
        for (int it = 0; it < 4; ++it) {
            const int lin = it * 256 + tid;
            const int row = lin >> 3;
            const int c4  = (lin & 7) * 4;
            uint4 va = *(const uint4*)&A[(size_t)(m0 + row) * K + kc + c4];
            uint2 ah, al;
            ah.x = (va.x >> 16) | (va.y & 0xffff0000u);
            ah.y = (va.z >> 16) | (va.w & 0xffff0000u);
            al.x = (va.x & 0xffffu) | (va.y << 16);
            al.y = (va.z & 0xffffu) | (va.w << 16);
            *(uint2*)&Ahi[row][c4] = ah;
            *(uint2*)&Alo[row][c4] = al;
            uint4 vw = *(const uint4*)&W[(size_t)(n0 + row) * K + kc + c4];
            uint2 wh, wl;
            wh.x = (vw.x >> 16) | (vw.y & 0xffff0000u);
            wh.y = (vw.z >> 16) | (vw.w & 0xffff0000u);
            wl.x = (vw.x & 0xffffu) | (vw.y << 16);
            wl.y = (vw.z & 0xffffu) | (vw.w << 16);
            *(uint2*)&Whi[row][c4] = wh;
            *(uint2*)&Wlo[row][c4] = wl;
        }
        __syncthreads();

        bf16x8 afh[4], afl[4], bfh[4], bfl[4];
        #pragma unroll
        for (int i = 0; i < 4; ++i) {
            afh[i] = *(const bf16x8*)&Ahi[wm + i * 16 + l15][quad * 8];
            afl[i] = *(const bf16x8*)&Alo[wm + i * 16 + l15][quad * 8];
            bfh[i] = *(const bf16x8*)&Whi[wn + i * 16 + l15][quad * 8];
            bfl[i] = *(const bf16x8*)&Wlo[wn + i * 16 + l15][quad * 8];
        }
        #pragma unroll
        for (int i = 0; i < 4; ++i)
            #pragma unroll
            for (int j = 0; j < 4; ++j) {
                acc[i][j] = __builtin_amdgcn_mfma_f32_16x16x32_bf16(afh[i], bfh[j], acc[i][j], 0, 0, 0);
                acc[i][j] = __builtin_amdgcn_mfma_f32_16x16x32_bf16(afh[i], bfl[j], acc[i][j], 0, 0, 0);
                acc[i][j] = __builtin_amdgcn_mfma_f32_16x16x32_bf16(afl[i], bfh[j], acc[i][j], 0, 0, 0);
            }
        __syncthreads();
    }

    #pragma unroll
    for (int i = 0; i < 4; ++i) {
        #pragma unroll
        for (int j = 0; j < 4; ++j) {
            const int n = n0 + wn + j * 16 + l15;
            const float bias = b0[n] + b1[n];
            #pragma unroll
            for (int r = 0; r < 4; ++r) {
                const int m = m0 + wm + i * 16 + quad * 4 + r;
                C[(size_t)m * N + n] = acc[i][j][r] + bias;
            }
        }
    }
}

// ---------------------------------------------------------------------------
// Stage 8 tagged h-cells into LDS hi/lo planes — ATOMIC (coherence-point)
// path. Retry fallback only; returns nonzero on tag miss.
// ---------------------------------------------------------------------------
__device__ __forceinline__ unsigned stage8_atomic(
    const unsigned long long* __restrict__ src, int bb, int kk, unsigned exp,
    short (*Hs_hi)[HP2], short (*Hs_lo)[HP2])
{
    unsigned long long q0 = __hip_atomic_load(src + 0, __ATOMIC_RELAXED, __HIP_MEMORY_SCOPE_AGENT);
    unsigned long long q1 = __hip_atomic_load(src + 1, __ATOMIC_RELAXED, __HIP_MEMORY_SCOPE_AGENT);
    unsigned long long q2 = __hip_atomic_load(src + 2, __ATOMIC_RELAXED, __HIP_MEMORY_SCOPE_AGENT);
    unsigned long long q3 = __hip_atomic_load(src + 3, __ATOMIC_RELAXED, __HIP_MEMORY_SCOPE_AGENT);
    unsigned c0 = (unsigned)q0, c1 = (unsigned)(q0 >> 32);
    unsigned c2 = (unsigned)q1, c3 = (unsigned)(q1 >> 32);
    unsigned c4 = (unsigned)q2, c5 = (unsigned)(q2 >> 32);
    unsigned c6 = (unsigned)q3, c7 = (unsigned)(q3 >> 32);
    unsigned bad = ((c0 ^ exp) | (c1 ^ exp) | (c2 ^ exp) | (c3 ^ exp)
                  | (c4 ^ exp) | (c5 ^ exp) | (c6 ^ exp) | (c7 ^ exp)) & 0xFu;
    uint4 hiv, lov;
    hiv.x = (c0 >> 16) | (c1 & 0xffff0000u);
    hiv.y = (c2 >> 16) | (c3 & 0xffff0000u);
    hiv.z = (c4 >> 16) | (c5 & 0xffff0000u);
    hiv.w = (c6 >> 16) | (c7 & 0xffff0000u);
    lov.x = (c0 & 0xFFF0u) | ((c1 & 0xFFF0u) << 16);
    lov.y = (c2 & 0xFFF0u) | ((c3 & 0xFFF0u) << 16);
    lov.z = (c4 & 0xFFF0u) | ((c5 & 0xFFF0u) << 16);
    lov.w = (c6 & 0xFFF0u) | ((c7 & 0xFFF0u) << 16);
    *(uint4*)&Hs_hi[bb][kk] = hiv;
    *(uint4*)&Hs_lo[bb][kk] = lov;
    return bad;
}

// ---------------------------------------------------------------------------
// Stage 8 tagged h-cells — PLAIN CACHED path (fast). Only issued after the
// flag handshake; tag check retained, mismatch handled by caller.
// ---------------------------------------------------------------------------
__device__ __forceinline__ unsigned stage8_plain(
    const unsigned* __restrict__ src, int bb, int kk, unsigned exp,
    short (*Hs_hi)[HP2], short (*Hs_lo)[HP2])
{
    const uint4 v0 = *(const uint4*)(src);
    const uint4 v1 = *(const uint4*)(src + 4);
    unsigned bad = ((v0.x ^ exp) | (v0.y ^ exp) | (v0.z ^ exp) | (v0.w ^ exp)
                  | (v1.x ^ exp) | (v1.y ^ exp) | (v1.z ^ exp) | (v1.w ^ exp)) & 0xFu;
    uint4 hiv, lov;
    hiv.x = (v0.x >> 16) | (v0.y & 0xffff0000u);
    hiv.y = (v0.z >> 16) | (v0.w & 0xffff0000u);
    hiv.z = (v1.x >> 16) | (v1.y & 0xffff0000u);
    hiv.w = (v1.z >> 16) | (v1.w & 0xffff0000u);
    lov.x = (v0.x & 0xFFF0u) | ((v0.y & 0xFFF0u) << 16);
    lov.y = (v0.z & 0xFFF0u) | ((v0.w & 0xFFF0u) << 16);
    lov.z = (v1.x & 0xFFF0u) | ((v1.y & 0xFFF0u) << 16);
    lov.w = (v1.z & 0xFFF0u) | ((v1.w & 0xFFF0u) << 16);
    *(uint4*)&Hs_hi[bb][kk] = hiv;
    *(uint4*)&Hs_lo[bb][kk] = lov;
    return bad;
}

// FAST+SAFE tile stage: one plain pass on the XCD-local ring; any tag miss
// retries from the agent-stored safe buffer (guaranteed progress, works
// regardless of block->XCD placement).
__device__ __forceinline__ void stage_tile_fs(
    const unsigned* __restrict__ fastb, const unsigned* __restrict__ safeb,
    unsigned exp, int tstart, int pcount, int pstride,
    short (*Hs_hi)[HP2], short (*Hs_lo)[HP2])
{
    unsigned miss = 0;
    for (int p = 0; p < pcount; ++p) {
        const int idx = p * pstride + tstart;
        unsigned bad = stage8_plain(fastb + idx, idx >> 9, idx & 511,
                                    exp, Hs_hi, Hs_lo);
        miss |= (bad ? 1u : 0u) << p;
    }
    while (miss) {
        for (int p = 0; p < pcount; ++p) {
            if (miss & (1u << p)) {
                const int idx = p * pstride + tstart;
                if (!stage8_atomic((const unsigned long long*)(safeb + idx),
                                   idx >> 9, idx & 511, exp, Hs_hi, Hs_lo))
                    miss &= ~(1u << p);
            }
        }
    }
}

// Plain pass + agent retry on the SAME (safe) base — for the cross-XCD X
// path (R2/R5-proven mechanism).
__device__ __forceinline__ void stage_tile_g(
    const unsigned* __restrict__ base, unsigned exp,
    int tstart, int pcount, int pstride,
    short (*Hs_hi)[HP2], short (*Hs_lo)[HP2])
{
    stage_tile_fs(base, base, exp, tstart, pcount, pstride, Hs_hi, Hs_lo);
}

// Agent-scope relaxed poll (R5-proven). BOUNDED: flags are a latency
// optimization only; tag-retry staging is a complete correctness protocol.
__device__ __forceinline__ void spin_flag(const unsigned* p) {
    int n = 0;
    while (__hip_atomic_load(p, __ATOMIC_RELAXED, __HIP_MEMORY_SCOPE_AGENT) == 0u) {
        if (++n > 65536) break;
    }
}

// ---------------------------------------------------------------------------
// FUSED two-layer persistent LSTM — R8: XCD-local h rings + R5 handshake.
//
// Block decode: c8 = blockIdx&7 selects clique (layer = c8>>2, bt = c8&3),
// jsl = blockIdx>>3. With round-robin blockIdx%8 -> XCD dispatch, each
// clique's 32 blocks land on ONE XCD (32 CUs) — producer h plain-stores
// land in that XCD's L2 and consumer plain loads hit it (~200cy vs ~600+
// at the coherence point). Producers DUAL-store: plain -> 4-slot ring
// (fast) AND agent -> hpack (safe; feeds cross-XCD X path + classifier).
// Consumers flag-gate (R5 protocol: B4 barrier + tid0 single agent flag
// store; wave0/wave4 poll), one plain pass on the ring, tag-miss falls
// back to agent retries on hpack. Placement assumption affects SPEED only
// (G16-safe): wrong mapping -> every stage degrades to the safe path.
// Ring WAR impossible: intra-clique skew < 4 steps, and 4 % 9 != 0 so
// tags catch any violation. 512 threads: waves 0-3 R pipe, 4-7 X pipe.
// ---------------------------------------------------------------------------
__global__ __launch_bounds__(512, 2) void lstm_fused(
    const float* __restrict__ xg,     // [T][B][4H] layer-0 (biases included)
    const float* __restrict__ w_hh0,  // [4H][H] fp32
    const float* __restrict__ w_ih1,  // [4H][H] fp32
    const float* __restrict__ w_hh1,  // [4H][H] fp32
    const float* __restrict__ b_ih1, const float* __restrict__ b_hh1,
    unsigned* __restrict__ hpack0,    // [T+1][B][H] tagged SAFE, block 0 zeroed
    unsigned* __restrict__ hpack1,    // [T+1][B][H] tagged SAFE, block 0 zeroed
    unsigned* __restrict__ ring0,     // [4][B][H] tagged FAST ring, slot 0 zeroed
    unsigned* __restrict__ ring1,     // [4][B][H] tagged FAST ring, slot 0 zeroed
    unsigned* __restrict__ flags)     // [2][T+1][4][32] step flags (zeroed)
{
    __shared__ short Ra_hi[32][HP2], Ra_lo[32][HP2];   // recurrent h tile
    __shared__ short Xa_hi[32][HP2], Xa_lo[32][HP2];   // layer-1 input h0 tile
    __shared__ float GsR[64][33];
    __shared__ float GsX[64][33];

    const int tid  = threadIdx.x;          // 0..511
    const int lane = tid & 63;
    const int wv   = tid >> 6;             // 0..7
    const bool isR = wv < 4;               // R-pipeline waves
    const int gate = wv & 3;               // gate for MFMA (both roles)
    const int c8   = blockIdx.x & 7;       // clique id == target XCD
    const bool isB = (c8 >> 2) != 0;
    const int bt   = c8 & 3;
    const int jsl  = blockIdx.x >> 3;      // producer j-slice id 0..31
    const int j0   = jsl * 16;             // 16-unit slice
    const int l15  = lane & 15;
    const int quad = lane >> 4;
    const int tid_x = tid - 256;           // X-thread linear id (valid if !isR)

    // ---- preload weight frags: ONE array per thread, role-dependent ----
    bf16x8 wf_hi[16], wf_lo[16];
    {
        const float* wsrc = isR ? (isB ? w_hh1 : w_hh0) : w_ih1;
        if (isR || isB) {
            const float* wrow = wsrc + (size_t)(gate * HH + j0 + l15) * HH + quad * 8;
            #pragma unroll
            for (int kc = 0; kc < 16; ++kc) {
                float f[8];
                *(float4*)&f[0] = *(const float4*)&wrow[kc * 32];
                *(float4*)&f[4] = *(const float4*)&wrow[kc * 32 + 4];
                bf16x8 vh, vl;
                #pragma unroll
                for (int j = 0; j < 8; ++j) {
                    unsigned short hb = f2bf(f[j]);
                    vh[j] = (short)hb;
                    vl[j] = (short)f2bf(f[j] - bf2f(hb));
                }
                wf_hi[kc] = vh; wf_lo[kc] = vl;
            }
        }
    }

    // update-phase roles (R-threads): 2 j-adjacent cells of one batch row
    const int ju  = (tid & 7) * 2;         // 0,2,...,14
    const int bu2 = (tid >> 3) & 31;       // 0..31
    float bi0=0.f,bi1=0.f,bf0_=0.f,bf1_=0.f,bg0=0.f,bg1=0.f,bo0=0.f,bo1=0.f;
    if (isB && isR) {
        bi0 = b_ih1[j0+ju]        + b_hh1[j0+ju];
        bi1 = b_ih1[j0+ju+1]      + b_hh1[j0+ju+1];
        bf0_= b_ih1[HH+j0+ju]     + b_hh1[HH+j0+ju];
        bf1_= b_ih1[HH+j0+ju+1]   + b_hh1[HH+j0+ju+1];
        bg0 = b_ih1[2*HH+j0+ju]   + b_hh1[2*HH+j0+ju];
        bg1 = b_ih1[2*HH+j0+ju+1] + b_hh1[2*HH+j0+ju+1];
        bo0 = b_ih1[3*HH+j0+ju]   + b_hh1[3*HH+j0+ju];
        bo1 = b_ih1[3*HH+j0+ju+1] + b_hh1[3*HH+j0+ju+1];
    }

    // zero GsX once (layer-0 never writes it; update always reads it)
    for (int i = tid; i < 64 * 33; i += 512)
        ((float*)GsX)[i] = 0.f;
    __syncthreads();

    unsigned* hp_safe = isB ? hpack1 : hpack0;
    unsigned* ring    = isB ? ring1  : ring0;
    const int layerBase = isB ? 65 : 0;
    float c0 = 0.f, c1 = 0.f;

    for (int t = 0; t < TT; ++t) {
        const unsigned* rec_fast = ring + (size_t)(t & 3) * (BB * HH) + (size_t)bt * 32 * HH;
        const unsigned* rec_safe = hp_safe + (size_t)t * (BB * HH) + (size_t)bt * 32 * HH;
        const unsigned* inp_base = hpack0 + (size_t)(t + 1) * (BB * HH) + (size_t)bt * 32 * HH;
        const unsigned expR = (unsigned)t % 9u;
        const unsigned expX = (unsigned)(t + 1) % 9u;
        const unsigned* fR = flags + ((layerBase + t) * 4 + bt) * 32;
        const unsigned* fX = flags + ((t + 1) * 4 + bt) * 32;

        // layer-0 R-threads: xg prefetch (overlaps poll + staging latency)
        float2 xgv[4];
        if (!isB && isR) {
            const float* base = xg + (size_t)t * (BB * GG)
                              + (size_t)(bt * 32 + bu2) * GG + j0 + ju;
            #pragma unroll
            for (int g = 0; g < 4; ++g)
                xgv[g] = *(const float2*)&base[g * HH];
        }

        // ---- polls: wave 0 -> 32 R-flags, wave 4 -> 32 X-flags ----
        if (wv == 0 && lane < 32 && t > 0 && lane != jsl) spin_flag(fR + lane);
        if (isB && wv == 4 && lane < 32) spin_flag(fX + lane);
        __syncthreads();                                   // B1

        // ---- staging (flag-gated; ring fast path, safe fallback) ----
        if (isB) {
            if (isR) stage_tile_fs(rec_fast, rec_safe, expR, tid * 8,   8, 2048, Ra_hi, Ra_lo);
            else     stage_tile_g (inp_base,           expX, tid_x * 8, 8, 2048, Xa_hi, Xa_lo);
        } else {
            stage_tile_fs(rec_fast, rec_safe, expR, tid * 8, 4, 4096, Ra_hi, Ra_lo);
        }
        __syncthreads();                                   // B2

        // ---- MFMA + Gs writes ----
        if (isR) {
            floatx4 a0 = {0.f,0.f,0.f,0.f}, a1 = {0.f,0.f,0.f,0.f};
            #pragma unroll
            for (int kc = 0; kc < 16; ++kc) {
                const int off = kc * 32 + quad * 8;
                bf16x8 r0h = *(const bf16x8*)&Ra_hi[l15][off];
                bf16x8 r0l = *(const bf16x8*)&Ra_lo[l15][off];
                bf16x8 r1h = *(const bf16x8*)&Ra_hi[16 + l15][off];
                bf16x8 r1l = *(const bf16x8*)&Ra_lo[16 + l15][off];
                a0 = __builtin_amdgcn_mfma_f32_16x16x32_bf16(wf_hi[kc], r0h, a0, 0, 0, 0);
                a1 = __builtin_amdgcn_mfma_f32_16x16x32_bf16(wf_hi[kc], r1h, a1, 0, 0, 0);
                a0 = __builtin_amdgcn_mfma_f32_16x16x32_bf16(wf_hi[kc], r0l, a0, 0, 0, 0);
                a1 = __builtin_amdgcn_mfma_f32_16x16x32_bf16(wf_hi[kc], r1l, a1, 0, 0, 0);
                a0 = __builtin_amdgcn_mfma_f32_16x16x32_bf16(wf_lo[kc], r0h, a0, 0, 0, 0);
                a1 = __builtin_amdgcn_mfma_f32_16x16x32_bf16(wf_lo[kc], r1h, a1, 0, 0, 0);
            }
            #pragma unroll
            for (int r = 0; r < 4; ++r) {
                GsR[gate * 16 + quad * 4 + r][l15]      = a0[r];
                GsR[gate * 16 + quad * 4 + r][16 + l15] = a1[r];
            }
        } else if (isB) {
            floatx4 a0 = {0.f,0.f,0.f,0.f}, a1 = {0.f,0.f,0.f,0.f};
            #pragma unroll
            for (int kc = 0; kc < 16; ++kc) {
                const int off = kc * 32 + quad * 8;
                bf16x8 x0h = *(const bf16x8*)&Xa_hi[l15][off];
                bf16x8 x0l = *(const bf16x8*)&Xa_lo[l15][off];
                bf16x8 x1h = *(const bf16x8*)&Xa_hi[16 + l15][off];
                bf16x8 x1l = *(const bf16x8*)&Xa_lo[16 + l15][off];
                a0 = __builtin_amdgcn_mfma_f32_16x16x32_bf16(wf_hi[kc], x0h, a0, 0, 0, 0);
                a1 = __builtin_amdgcn_mfma_f32_16x16x32_bf16(wf_hi[kc], x1h, a1, 0, 0, 0);
                a0 = __builtin_amdgcn_mfma_f32_16x16x32_bf16(wf_hi[kc], x0l, a0, 0, 0, 0);
                a1 = __builtin_amdgcn_mfma_f32_16x16x32_bf16(wf_hi[kc], x1l, a1, 0, 0, 0);
                a0 = __builtin_amdgcn_mfma_f32_16x16x32_bf16(wf_lo[kc], x0h, a0, 0, 0, 0);
                a1 = __builtin_amdgcn_mfma_f32_16x16x32_bf16(wf_lo[kc], x1h, a1, 0, 0, 0);
            }
            #pragma unroll
            for (int r = 0; r < 4; ++r) {
                GsX[gate * 16 + quad * 4 + r][l15]      = a0[r];
                GsX[gate * 16 + quad * 4 + r][16 + l15] = a1[r];
            }
        }
        __syncthreads();                                   // B3

        // ---- update (R-threads): 2 cells; DUAL tagged 8B store ----
        if (isR) {
            const unsigned tag = (unsigned)(t + 1) % 9u;
            float gi0 = GsR[ju][bu2]      + GsX[ju][bu2];
            float gi1 = GsR[ju+1][bu2]    + GsX[ju+1][bu2];
            float gf0 = GsR[16+ju][bu2]   + GsX[16+ju][bu2];
            float gf1 = GsR[17+ju][bu2]   + GsX[17+ju][bu2];
            float gg0 = GsR[32+ju][bu2]   + GsX[32+ju][bu2];
            float gg1 = GsR[33+ju][bu2]   + GsX[33+ju][bu2];
            float go0 = GsR[48+ju][bu2]   + GsX[48+ju][bu2];
            float go1 = GsR[49+ju][bu2]   + GsX[49+ju][bu2];
            if (isB) {
                gi0 += bi0; gi1 += bi1; gf0 += bf0_; gf1 += bf1_;
                gg0 += bg0; gg1 += bg1; go0 += bo0; go1 += bo1;
            } else {
                gi0 += xgv[0].x; gi1 += xgv[0].y;
                gf0 += xgv[1].x; gf1 += xgv[1].y;
                gg0 += xgv[2].x; gg1 += xgv[2].y;
                go0 += xgv[3].x; go1 += xgv[3].y;
            }
            const float si0 = 1.f / (1.f + __expf(-gi0));
            const float sf0 = 1.f / (1.f + __expf(-gf0));
            const float tg0 = 2.f / (1.f + __expf(-2.f * gg0)) - 1.f;
            const float so0 = 1.f / (1.f + __expf(-go0));
            c0 = sf0 * c0 + si0 * tg0;
            const float th0 = 2.f / (1.f + __expf(-2.f * c0)) - 1.f;
            const float h0v = so0 * th0;
            const float si1 = 1.f / (1.f + __expf(-gi1));
            const float sf1 = 1.f / (1.f + __expf(-gf1));
            const float tg1 = 2.f / (1.f + __expf(-2.f * gg1)) - 1.f;
            const float so1 = 1.f / (1.f + __expf(-go1));
            c1 = sf1 * c1 + si1 * tg1;
            const float th1 = 2.f / (1.f + __expf(-2.f * c1)) - 1.f;
            const float h1v = so1 * th1;
            const unsigned short hb0 = f2bf(h0v);
            const unsigned short lb0 = f2bf(h0v - bf2f(hb0));
            const unsigned short hb1 = f2bf(h1v);
            const unsigned short lb1 = f2bf(h1v - bf2f(hb1));
            const unsigned pk0 = ((unsigned)hb0 << 16) | ((unsigned)lb0 & 0xFFF0u) | tag;
            const unsigned pk1 = ((unsigned)hb1 << 16) | ((unsigned)lb1 & 0xFFF0u) | tag;
            const unsigned long long pk64 =
                (unsigned long long)pk0 | ((unsigned long long)pk1 << 32);
            const size_t cell = (size_t)(bt * 32 + bu2) * HH + j0 + ju;
            // FAST: plain store into this XCD's L2 (ring slot (t+1)&3)
            *(unsigned long long*)&ring[(size_t)((t + 1) & 3) * (BB * HH) + cell] = pk64;
            // SAFE: agent store to the coherence point (X path + fallback + cls)
            __hip_atomic_store(
                (unsigned long long*)&hp_safe[(size_t)(t + 1) * (BB * HH) + cell],
                pk64, __ATOMIC_RELAXED, __HIP_MEMORY_SCOPE_AGENT);
        }
        __syncthreads();                                   // B4 (drains stores)

        // ---- publish: single flag store for this slice (R5-proven) ----
        if (tid == 0)
            __hip_atomic_store(
                flags + ((layerBase + (t + 1)) * 4 + bt) * 32 + jsl,
                1u, __ATOMIC_RELAXED, __HIP_MEMORY_SCOPE_AGENT);
    }
}

// ---------------------------------------------------------------------------
// Classifier split-K partial GEMM on tagged h cells (mask tag nibble)
// ---------------------------------------------------------------------------
__global__ __launch_bounds__(256) void cls_partial_kernel(
    const unsigned* __restrict__ A, const float* __restrict__ W,
    float* __restrict__ part)
{
    const int n0 = blockIdx.x * 64;
    const int s  = blockIdx.y;
    const int kbase = s * 2048;
    const int tid = threadIdx.x;
    __shared__ float As[32][68];
    __shared__ float Bs[32][68];
    const int tm = tid >> 4, tn = tid & 15;
    float acc[4][4] = {};

    for (int kt = 0; kt < 2048; kt += 32) {
        #pragma unroll
        for (int q = tid; q < 512; q += 256) {
            const int mm = q >> 3;
            const int kq = q & 7;
            uint4 v = *(const uint4*)&A[(size_t)mm * KFLAT + kbase + kt + kq * 4];
            As[kq*4+0][mm] = pk2f(v.x & 0xFFFFFFF0u); As[kq*4+1][mm] = pk2f(v.y & 0xFFFFFFF0u);
            As[kq*4+2][mm] = pk2f(v.z & 0xFFFFFFF0u); As[kq*4+3][mm] = pk2f(v.w & 0xFFFFFFF0u);
            float4 w = *(const float4*)&W[(size_t)(n0 + mm) * KFLAT + kbase + kt + kq * 4];
            Bs[kq*4+0][mm] = w.x; Bs[kq*4+1][mm] = w.y;
            Bs[kq*4+2][mm] = w.z; Bs[kq*4+3][mm] = w.w;
        }
        __syncthreads();
        #pragma unroll
        for (int k = 0; k < 32; ++k) {
            float4 a = *(const float4*)&As[k][tm * 4];
            float4 b = *(const float4*)&Bs[k][tn * 4];
            acc[0][0] += a.x*b.x; acc[0][1] += a.x*b.y; acc[0][2] += a.x*b.z; acc[0][3] += a.x*b.w;
            acc[1][0] += a.y*b.x; acc[1][1] += a.y*b.y; acc[1][2] += a.y*b.z; acc[1][3] += a.y*b.w;
            acc[2][0] += a.z*b.x; acc[2][1] += a.z*b.y; acc[2][2] += a.z*b.z; acc[2][3] += a.z*b.w;
            acc[3][0] += a.w*b.x; acc[3][1] += a.w*b.y; acc[3][2] += a.w*b.z; acc[3][3] += a.w*b.w;
        }
        __syncthreads();
    }
    #pragma unroll
    for (int i = 0; i < 4; ++i) {
        const int m = tm * 4 + i;
        #pragma unroll
        for (int j = 0; j < 4; ++j) {
            part[((size_t)s * 64 + m) * 512 + n0 + tn * 4 + j] = acc[i][j];
        }
    }
}

// ---------------------------------------------------------------------------
// Classifier finish (unchanged)
// ---------------------------------------------------------------------------
__global__ __launch_bounds__(256) void cls_final_kernel(
    const float* __restrict__ part, const float* __restrict__ b1,
    const float* __restrict__ w2, const float* __restrict__ b2,
    float* __restrict__ out)
{
    const int t = blockIdx.x;
    __shared__ float hm[512];
    for (int n = threadIdx.x; n < 512; n += 256) {
        float sacc = b1[n];
        for (int sl = 0; sl < 32; ++sl)
            sacc += part[((size_t)sl * 64 + t) * 512 + n];
        hm[n] = fmaxf(sacc, 0.f);
    }
    __syncthreads();
    if (threadIdx.x < NCC) {
        float sacc = b2[threadIdx.x];
        const float* wr = w2 + (size_t)threadIdx.x * 512;
        for (int n = 0; n < 512; ++n) sacc += hm[n] * wr[n];
        out[t * NCC + threadIdx.x] = sacc;
    }
}

// ---------------------------------------------------------------------------
extern "C" void kernel_launch(void* const* d_in, const int* in_sizes, int n_in,
                              void* d_out, int out_size, void* d_ws, size_t ws_size,
                              hipStream_t stream)
{
    const float* x     = (const float*)d_in[0];
    const float* w_ih0 = (const float*)d_in[1];
    const float* w_hh0 = (const float*)d_in[2];
    const float* b_ih0 = (const float*)d_in[3];
    const float* b_hh0 = (const float*)d_in[4];
    const float* w_ih1 = (const float*)d_in[5];
    const float* w_hh1 = (const float*)d_in[6];
    const float* b_ih1 = (const float*)d_in[7];
    const float* b_hh1 = (const float*)d_in[8];
    const float* w1    = (const float*)d_in[9];
    const float* b1    = (const float*)d_in[10];
    const float* w2    = (const float*)d_in[11];
    const float* b2    = (const float*)d_in[12];
    float* out = (float*)d_out;

    // Workspace (~102.1 MB, unchanged): hpack1 aliases xpk/w0pk (dead after
    // the layer-0 GEMM). flags + rings alias the part region (part written
    // only after lstm_fused completes): flags@+0 (66.6KB), ring0@+1MB (1MB),
    // ring1@+2MB (1MB) — all within part's 4MB.
    float*    ws     = (float*)d_ws;
    float*    xg     = ws;                                      // 64 MB
    unsigned* hpack0 = (unsigned*)(xg + (size_t)8192 * 2048);   // 17.04 MB
    unsigned* hpack1 = hpack0 + (size_t)65 * BB * HH;           // 17.04 MB (aliased)
    unsigned* xpk    = hpack1;                                  // 8 MB   (dies at GEMM)
    unsigned* w0pk   = xpk + (size_t)8192 * IND;                // 2 MB   (dies at GEMM)
    float*    part   = (float*)(hpack1 + (size_t)65 * BB * HH); // 4 MB
    unsigned* flags  = (unsigned*)part;                         // 66.6 KB (dies at cls)
    unsigned* ring0  = (unsigned*)((char*)part + (1 << 20));    // 1 MB (dies at cls)
    unsigned* ring1  = (unsigned*)((char*)part + (2 << 20));    // 1 MB (dies at cls)

    // ---- pack layer-0 GEMM inputs ----
    pack_split_kernel<<<1024, 256, 0, stream>>>(x, xpk, 8192 * IND);
    pack_split_kernel<<<512,  256, 0, stream>>>(w_ih0, w0pk, GG * IND);
    hipMemsetAsync(hpack0, 0, (size_t)BB * HH * sizeof(unsigned), stream);  // h0 t=0
    hipMemsetAsync(flags, 0, (size_t)2 * 65 * 4 * 32 * sizeof(unsigned), stream);
    hipMemsetAsync(ring0, 0, (size_t)BB * HH * sizeof(unsigned), stream);   // slot 0
    hipMemsetAsync(ring1, 0, (size_t)BB * HH * sizeof(unsigned), stream);   // slot 0

    // ---- layer-0 input transform ----
    gemm_pk_mfma<<<dim3(8192 / 128, GG / 128), 256, 0, stream>>>(
        xpk, w0pk, b_ih0, b_hh0, xg, IND, GG);

    // ---- zero t=0 block of hpack1 (after GEMM: aliased region now dead) ----
    hipMemsetAsync(hpack1, 0, (size_t)BB * HH * sizeof(unsigned), stream);

    // ---- fused two-layer recurrence (XCD-local cliques) ----
    lstm_fused<<<256, 512, 0, stream>>>(
        xg, w_hh0, w_ih1, w_hh1, b_ih1, b_hh1, hpack0, hpack1, ring0, ring1, flags);

    // ---- classifier (tagged h1 safe buffer, blocks 1..64) ----
    cls_partial_kernel<<<dim3(512 / 64, 32), 256, 0, stream>>>(
        hpack1 + (size_t)BB * HH, w1, part);
    cls_final_kernel<<<64, 256, 0, stream>>>(part, b1, w2, b2, out);
}